// Round 2
// baseline (5491.560 us; speedup 1.0000x reference)
//
#include <hip/hip_runtime.h>

#define DEVI __device__ __forceinline__
typedef float f2 __attribute__((ext_vector_type(2)));

// ---------------- problem constants ----------------
constexpr int T_ = 4096, B_ = 128;
constexpr int CH = 4, NCH = T_ / CH;   // 1024 chunks of 4 timesteps
constexpr int NSTEP2 = 1040;           // >= NCH + 15 stages, even
constexpr int XROW = 68;               // x row padded 64->68 dwords

// One batch per workgroup. LDS strides in floats.
// y1/xw layer block: [2][CH][20] -> sl*80 + tt*20 + j
// y2 layer block:    [2][CH][12] -> sl*48 + tt*12 + j  (slots 10,11 are zero pads)
constexpr int Y1L = 160, Y2L = 96;

struct P {
  const float* x;
  const float* w1; const float* b1;    // wih0 (20x64), bih0 (20)
  const float* wih[31]; const float* whh[31];
  const float* bih[31]; const float* bhh[31];
  float* out;
};

DEVI float ftanh(float x) {
  float e = __builtin_amdgcn_exp2f(x * 2.8853900817779268f);
  return 1.0f - 2.0f * __builtin_amdgcn_rcpf(e + 1.0f);
}

DEVI f2 pfma(f2 a, f2 b, f2 c) { return __builtin_elementwise_fma(a, b, c); }

// lane-broadcast: pull 32b value from lane (idx>>2)
DEVI float bperm(int idx, float v) {
  return __int_as_float(__builtin_amdgcn_ds_bpermute(idx, __float_as_int(v)));
}

// combine the two lane-halves (lane j <-> lane j^32); both halves get the full sum
DEVI float redsumf(float s, int pidx) {
  return s + __int_as_float(__builtin_amdgcn_ds_bpermute(pidx, __float_as_int(s)));
}

// half-dot over 10 floats from LDS (broadcast rows): 5 ds_read_b64 + 5 v_pk_fma
DEVI void acc20h(f2& a, const float* r, const f2* w) {
#pragma unroll
  for (int q = 0; q < 5; q++) {
    float2 v = ((const float2*)r)[q];
    f2 t; t.x = v.x; t.y = v.y;
    a = pfma(t, w[q], a);
  }
}

// half-dot over 6 slots of a 12-slot padded row (slots 10,11 zero)
DEVI void acc12h(f2& a, const float* r, const f2* w) {
#pragma unroll
  for (int q = 0; q < 3; q++) {
    float2 v = ((const float2*)r)[q];
    f2 t; t.x = v.x; t.y = v.y;
    a = pfma(t, w[q], a);
  }
}

// ================= wave 0: x staging + input projection =================
template <int SL>
DEVI void proj_chunk(const float* xbh, float* xww, const f2* wp, float bp,
                     bool hi, int pidx) {
#pragma unroll
  for (int tt = 0; tt < CH; tt++) {
    const float* xr = xbh + SL * (CH * XROW) + tt * XROW;
    f2 a; a.x = bp; a.y = 0.f;
#pragma unroll
    for (int q = 0; q < 8; q++) {
      float4 v = ((const float4*)xr)[q];
      union { float4 f; f2 h[2]; } u; u.f = v;
      a = pfma(u.h[0], wp[2 * q], a);
      a = pfma(u.h[1], wp[2 * q + 1], a);
    }
    const float s = redsumf(a.x + a.y, pidx);
    if (!hi) xww[SL * 80 + tt * 20] = s;
  }
}

DEVI void stage_proj(const P& p, int b, int lane, float* xb, float* xwf) {
  const int jj = lane & 31;
  const bool act = jj < 20;
  const bool hi = lane >= 32;
  const int pidx = (lane ^ 32) << 2;
  const int j = act ? jj : 19;
  const int ko = hi ? 32 : 0;
  f2 wp[16];
#pragma unroll
  for (int k = 0; k < 16; k++) {
    wp[k].x = p.w1[j * 64 + ko + 2 * k]; wp[k].y = p.w1[j * 64 + ko + 2 * k + 1];
  }
  const float bp = hi ? 0.f : p.b1[j];
  float* xww = xwf + j;
  const float* xbh = xb + ko;

  // staging: all 64 lanes, one float4 each covers CH*64 = 256 floats
  const int tq = lane >> 4, qq = lane & 15;
  const float* src = p.x + (size_t)tq * (B_ * 64) + (size_t)b * 64 + qq * 4;
  const int dst = tq * XROW + qq * 4;
  float4 pf = *(const float4*)src;
  *(float4*)(xb + dst) = pf;
  src += CH * B_ * 64;

  for (int s = 0; s < NSTEP2; s += 2) {
    {  // phase A: c = s, slot 0
      const int c = s;
      if (c < NCH) {
        const bool more = (c + 1 < NCH);
        float4 nx;
        if (more) { nx = *(const float4*)src; src += CH * B_ * 64; }
        if (act) proj_chunk<0>(xbh, xww, wp, bp, hi, pidx);
        if (more) *(float4*)(xb + CH * XROW + dst) = nx;  // slot 1
      }
      __syncthreads();
    }
    {  // phase B: c = s+1, slot 1
      const int c = s + 1;
      if (c < NCH) {
        const bool more = (c + 1 < NCH);
        float4 nx;
        if (more) { nx = *(const float4*)src; src += CH * B_ * 64; }
        if (act) proj_chunk<1>(xbh, xww, wp, bp, hi, pidx);
        if (more) *(float4*)(xb + dst) = nx;  // slot 0
      }
      __syncthreads();
    }
  }
}

// ================= stack1 pair wave (2 layers, H=20) =================
// Recurrent state hA,hB lives in VGPRs (lanes 0..19 & 32..51 hold h_j).
// Per-term ds_bpermute broadcasts h_k to all lanes; no LDS round trip.
template <int SL, bool FIRST>
DEVI void pair_chunk(const float* yin, float* yBw, float& hA, float& hB,
                     const f2* wiAp, const float* whAs, const float* wiBs,
                     const float* whBs, float bA, float bB, bool hi, int bb,
                     int pidx) {
#pragma unroll
  for (int tt = 0; tt < CH; tt++) {
    const int IN = SL * 80 + tt * 20;
    f2 a; a.x = bA; a.y = 0.f;
    if constexpr (FIRST) {
      if (!hi) a.x += yin[IN];         // proj already = wih0.x + bih0 (scalar per j)
    } else {
      acc20h(a, yin + IN, wiAp);       // prev layer's row from LDS (off chain)
    }
    float r0 = 0.f, r1 = 0.f;
#pragma unroll
    for (int k = 0; k < 10; k++) {
      const float v = bperm(bb + 4 * k, hA);
      if (k & 1) r1 = fmaf(v, whAs[k], r1);
      else       r0 = fmaf(v, whAs[k], r0);
    }
    hA = ftanh(redsumf(a.x + a.y + r0 + r1, pidx));
    float c0 = bB, c1 = 0.f;
#pragma unroll
    for (int k = 0; k < 10; k++) {     // hB side first: its source is older
      const float u = bperm(bb + 4 * k, hB);
      if (k & 1) c1 = fmaf(u, whBs[k], c1);
      else       c0 = fmaf(u, whBs[k], c0);
    }
#pragma unroll
    for (int k = 0; k < 10; k++) {
      const float v = bperm(bb + 4 * k, hA);
      if (k & 1) c1 = fmaf(v, wiBs[k], c1);
      else       c0 = fmaf(v, wiBs[k], c0);
    }
    hB = ftanh(redsumf(c0 + c1, pidx));
    if (!hi) yBw[IN] = hB;             // only B-layer rows are consumed cross-wave
  }
}

template <bool PH, bool FIRST>
DEVI void pair_s1(int la, int w, const P& p, int lane, float* y1f, float* xwf) {
  const int jj = lane & 31;
  const bool act = jj < 20;
  const bool hi = lane >= 32;
  const int pidx = (lane ^ 32) << 2;
  const int j = act ? jj : 19;
  const int ko = hi ? 10 : 0;          // term offset for this half
  const int bb = hi ? 40 : 0;          // bpermute byte base: hi terms 10..19 -> lanes 10..19
  const int lb = la + 1;
  float whAs[10], whBs[10], wiBs[10];
  f2 wiAp[FIRST ? 1 : 5];
#pragma unroll
  for (int k = 0; k < 10; k++) {
    whAs[k] = p.whh[la][j * 20 + ko + k];
    whBs[k] = p.whh[lb][j * 20 + ko + k];
    wiBs[k] = p.wih[lb][j * 20 + ko + k];
  }
  if constexpr (!FIRST) {
#pragma unroll
    for (int q = 0; q < 5; q++) {
      wiAp[q].x = p.wih[la][j * 20 + ko + 2 * q];
      wiAp[q].y = p.wih[la][j * 20 + ko + 2 * q + 1];
    }
  }
  float bA = hi ? 0.f : p.bhh[la][j];
  if constexpr (!FIRST) { if (!hi) bA += p.bih[la][j]; }  // L0: bih folded into proj
  const float bB = hi ? 0.f : (p.bih[lb][j] + p.bhh[lb][j]);

  const float* yin = FIRST ? (xwf + j) : (y1f + (la - 1) * Y1L + ko);
  float* yBw = y1f + lb * Y1L + j;
  float hA = 0.f, hB = 0.f;

  for (int s = 0; s < NSTEP2; s += 2) {
    if ((unsigned)(s - w) < (unsigned)NCH && act)
      pair_chunk<PH ? 1 : 0, FIRST>(yin, yBw, hA, hB, wiAp, whAs, wiBs, whBs,
                                    bA, bB, hi, bb, pidx);
    __syncthreads();
    if ((unsigned)(s + 1 - w) < (unsigned)NCH && act)
      pair_chunk<PH ? 0 : 1, FIRST>(yin, yBw, hA, hB, wiAp, whAs, wiBs, whBs,
                                    bA, bB, hi, bb, pidx);
    __syncthreads();
  }
}

// ================= wave 11: L20 (20->10) + L21 + L22 =================
template <int SL>
DEVI void tri20_chunk(const float* y19, float* y2w, float& h0, float& h1,
                      float& h2, const f2* wi0p, const float* wh0s,
                      const float* wi1s, const float* wh1s, const float* wi2s,
                      const float* wh2s, float b0, float b1, float b2,
                      bool hi, int bb, int pidx) {
#pragma unroll
  for (int tt = 0; tt < CH; tt++) {
    const int IN1 = SL * 80 + tt * 20;
    const int IN2 = SL * 48 + tt * 12;
    f2 a; a.x = b0; a.y = 0.f;
    acc20h(a, y19 + IN1, wi0p);
    float r = 0.f;
#pragma unroll
    for (int k = 0; k < 5; k++) r = fmaf(bperm(bb + 4 * k, h0), wh0s[k], r);
    h0 = ftanh(redsumf(a.x + a.y + r, pidx));
    float c = b1;
#pragma unroll
    for (int k = 0; k < 5; k++) c = fmaf(bperm(bb + 4 * k, h1), wh1s[k], c);
#pragma unroll
    for (int k = 0; k < 5; k++) c = fmaf(bperm(bb + 4 * k, h0), wi1s[k], c);
    h1 = ftanh(redsumf(c, pidx));
    float d = b2;
#pragma unroll
    for (int k = 0; k < 5; k++) d = fmaf(bperm(bb + 4 * k, h2), wh2s[k], d);
#pragma unroll
    for (int k = 0; k < 5; k++) d = fmaf(bperm(bb + 4 * k, h1), wi2s[k], d);
    h2 = ftanh(redsumf(d, pidx));
    if (!hi) y2w[IN2] = h2;            // only L22's row (ring row 2) is consumed
  }
}

template <bool PH>
DEVI void tri20(const P& p, int w, int lane, float* y1f, float* y2f) {
  const int jj = lane & 31;
  const bool act = jj < 10;
  const bool hi = lane >= 32;
  const int pidx = (lane ^ 32) << 2;
  const int j = act ? jj : 9;
  const int ko1 = hi ? 10 : 0;         // input (20-dim) half offset
  const int ko2 = hi ? 5 : 0;          // H=10 term half offset
  const int bb = hi ? 20 : 0;          // bpermute base: hi terms 5..9 -> lanes 5..9
  f2 wi0p[5];
  float wh0s[5], wi1s[5], wh1s[5], wi2s[5], wh2s[5];
#pragma unroll
  for (int q = 0; q < 5; q++) {
    wi0p[q].x = p.wih[20][j * 20 + ko1 + 2 * q];
    wi0p[q].y = p.wih[20][j * 20 + ko1 + 2 * q + 1];
  }
#pragma unroll
  for (int k = 0; k < 5; k++) {
    wh0s[k] = p.whh[20][j * 10 + ko2 + k];
    wi1s[k] = p.wih[21][j * 10 + ko2 + k];
    wh1s[k] = p.whh[21][j * 10 + ko2 + k];
    wi2s[k] = p.wih[22][j * 10 + ko2 + k];
    wh2s[k] = p.whh[22][j * 10 + ko2 + k];
  }
  const float b0 = hi ? 0.f : (p.bih[20][j] + p.bhh[20][j]);
  const float b1 = hi ? 0.f : (p.bih[21][j] + p.bhh[21][j]);
  const float b2 = hi ? 0.f : (p.bih[22][j] + p.bhh[22][j]);

  const float* y19 = y1f + 19 * Y1L + ko1;
  float* y2w = y2f + 2 * Y2L + j;
  float h0 = 0.f, h1 = 0.f, h2 = 0.f;

  // zero ALL of y2 once (pad slots [10],[11] read by hi-half acc12h consumers);
  // consumers first read >= 12 barriers later, so this is race-free.
  for (int q = lane; q < 10 * Y2L; q += 64) y2f[q] = 0.f;

  for (int s = 0; s < NSTEP2; s += 2) {
    if ((unsigned)(s - w) < (unsigned)NCH && act)
      tri20_chunk<PH ? 1 : 0>(y19, y2w, h0, h1, h2, wi0p, wh0s, wi1s, wh1s,
                              wi2s, wh2s, b0, b1, b2, hi, bb, pidx);
    __syncthreads();
    if ((unsigned)(s + 1 - w) < (unsigned)NCH && act)
      tri20_chunk<PH ? 0 : 1>(y19, y2w, h0, h1, h2, wi0p, wh0s, wi1s, wh1s,
                              wi2s, wh2s, b0, b1, b2, hi, bb, pidx);
    __syncthreads();
  }
}

// ================= waves 12/13: three H=10 layers =================
template <int SL>
DEVI void tri_chunk(const float* yi0, float* wout, float& h0, float& h1,
                    float& h2, const f2* wi0p, const float* wh0s,
                    const float* wi1s, const float* wh1s, const float* wi2s,
                    const float* wh2s, const float* bs, bool hi, int bb,
                    int pidx) {
#pragma unroll
  for (int tt = 0; tt < CH; tt++) {
    const int IN2 = SL * 48 + tt * 12;
    f2 a; a.x = bs[0]; a.y = 0.f;
    acc12h(a, yi0 + IN2, wi0p);        // ring-row input from LDS (off chain)
    float r = 0.f;
#pragma unroll
    for (int k = 0; k < 5; k++) r = fmaf(bperm(bb + 4 * k, h0), wh0s[k], r);
    h0 = ftanh(redsumf(a.x + a.y + r, pidx));
    float c = bs[1];
#pragma unroll
    for (int k = 0; k < 5; k++) c = fmaf(bperm(bb + 4 * k, h1), wh1s[k], c);
#pragma unroll
    for (int k = 0; k < 5; k++) c = fmaf(bperm(bb + 4 * k, h0), wi1s[k], c);
    h1 = ftanh(redsumf(c, pidx));
    float d = bs[2];
#pragma unroll
    for (int k = 0; k < 5; k++) d = fmaf(bperm(bb + 4 * k, h2), wh2s[k], d);
#pragma unroll
    for (int k = 0; k < 5; k++) d = fmaf(bperm(bb + 4 * k, h1), wi2s[k], d);
    h2 = ftanh(redsumf(d, pidx));
    if (!hi) wout[IN2] = h2;           // only last layer's row is consumed
  }
}

template <bool PH>
DEVI void tri_s2(int l0, int w, const P& p, int lane, float* y2f) {
  const int jj = lane & 31;
  const bool act = jj < 10;
  const bool hi = lane >= 32;
  const int pidx = (lane ^ 32) << 2;
  const int j = act ? jj : 9;
  const int ko6 = hi ? 6 : 0;          // LDS 12-slot half offset
  const int ko2 = hi ? 5 : 0;          // term half offset
  const int bb = hi ? 20 : 0;
  f2 wi0p[3];
  float wh0s[5], wi1s[5], wh1s[5], wi2s[5], wh2s[5];
  float bs[3];
#pragma unroll
  for (int q = 0; q < 3; q++) {
    const int i0 = ko6 + 2 * q, i1 = i0 + 1;
    wi0p[q].x = i0 < 10 ? p.wih[l0][j * 10 + i0] : 0.f;
    wi0p[q].y = i1 < 10 ? p.wih[l0][j * 10 + i1] : 0.f;
  }
#pragma unroll
  for (int k = 0; k < 5; k++) {
    wh0s[k] = p.whh[l0][j * 10 + ko2 + k];
    wi1s[k] = p.wih[l0 + 1][j * 10 + ko2 + k];
    wh1s[k] = p.whh[l0 + 1][j * 10 + ko2 + k];
    wi2s[k] = p.wih[l0 + 2][j * 10 + ko2 + k];
    wh2s[k] = p.whh[l0 + 2][j * 10 + ko2 + k];
  }
#pragma unroll
  for (int m = 0; m < 3; m++)
    bs[m] = hi ? 0.f : (p.bih[l0 + m][j] + p.bhh[l0 + m][j]);

  const int bi = l0 - 21;              // input ring row
  const float* yi0 = y2f + bi * Y2L + ko6;
  float* wout = y2f + (bi + 3) * Y2L + j;
  float h0 = 0.f, h1 = 0.f, h2 = 0.f;

  for (int s = 0; s < NSTEP2; s += 2) {
    if ((unsigned)(s - w) < (unsigned)NCH && act)
      tri_chunk<PH ? 1 : 0>(yi0, wout, h0, h1, h2, wi0p, wh0s, wi1s, wh1s,
                            wi2s, wh2s, bs, hi, bb, pidx);
    __syncthreads();
    if ((unsigned)(s + 1 - w) < (unsigned)NCH && act)
      tri_chunk<PH ? 0 : 1>(yi0, wout, h0, h1, h2, wi0p, wh0s, wi1s, wh1s,
                            wi2s, wh2s, bs, hi, bb, pidx);
    __syncthreads();
  }
}

// ================= wave 14: L29 (H=10) + L30 (H=1) + stores =================
template <int SL>
DEVI void tail_chunk(const float* y8r, float& h29, float& h30,
                     const f2* wi29p, const float* wh29s, const float* wi30s,
                     float b29, float b30, float wh30,
                     float*& optr, bool st, int bb, int pidx) {
#pragma unroll
  for (int tt = 0; tt < CH; tt++) {
    const int IN2 = SL * 48 + tt * 12;
    f2 a; a.x = b29; a.y = 0.f;
    acc12h(a, y8r + IN2, wi29p);
    float r = 0.f;
#pragma unroll
    for (int k = 0; k < 5; k++) r = fmaf(bperm(bb + 4 * k, h29), wh29s[k], r);
    h29 = ftanh(redsumf(a.x + a.y + r, pidx));
    float c = b30;
#pragma unroll
    for (int k = 0; k < 5; k++) c = fmaf(bperm(bb + 4 * k, h29), wi30s[k], c);
    const float s3 = redsumf(c, pidx); // full dot in all lanes
    h30 = ftanh(fmaf(h30, wh30, s3));  // all lanes track same h30
    if (st) optr[tt * B_] = h30;
  }
  optr += CH * B_;
}

template <bool PH>
DEVI void tail29(const P& p, int w, int b, int lane, float* y2f) {
  const int jj = lane & 31;
  const bool act = jj < 10;
  const bool hi = lane >= 32;
  const int pidx = (lane ^ 32) << 2;
  const int j = act ? jj : 9;
  const int ko6 = hi ? 6 : 0;
  const int ko2 = hi ? 5 : 0;
  const int bb = hi ? 20 : 0;
  const bool st = (lane == 0);
  f2 wi29p[3];
  float wh29s[5], wi30s[5];
#pragma unroll
  for (int q = 0; q < 3; q++) {
    const int i0 = ko6 + 2 * q, i1 = i0 + 1;
    wi29p[q].x = i0 < 10 ? p.wih[29][j * 10 + i0] : 0.f;
    wi29p[q].y = i1 < 10 ? p.wih[29][j * 10 + i1] : 0.f;
  }
#pragma unroll
  for (int k = 0; k < 5; k++) {
    wh29s[k] = p.whh[29][j * 10 + ko2 + k];
    wi30s[k] = p.wih[30][ko2 + k];     // single output row
  }
  const float b29 = hi ? 0.f : (p.bih[29][j] + p.bhh[29][j]);
  const float b30 = hi ? 0.f : (p.bih[30][0] + p.bhh[30][0]);
  const float wh30 = p.whh[30][0];     // applied post-reduction, all lanes
  float h29 = 0.f, h30 = 0.f;
  const float* y8r = y2f + 8 * Y2L + ko6;
  float* optr = p.out + b;

  for (int s = 0; s < NSTEP2; s += 2) {
    if ((unsigned)(s - w) < (unsigned)NCH && act)
      tail_chunk<PH ? 1 : 0>(y8r, h29, h30, wi29p, wh29s, wi30s, b29, b30,
                             wh30, optr, st, bb, pidx);
    __syncthreads();
    if ((unsigned)(s + 1 - w) < (unsigned)NCH && act)
      tail_chunk<PH ? 0 : 1>(y8r, h29, h30, wi29p, wh29s, wi30s, b29, b30,
                             wh30, optr, st, bb, pidx);
    __syncthreads();
  }
  if (st) p.out[T_ * B_ + b] = h30;    // hT
}

// ================= kernel =================
__global__ __launch_bounds__(960, 4) void rnn_fused(P p) {
  __shared__ alignas(16) float xbuf[2 * CH * XROW];  // 2.2 KB staged x
  __shared__ alignas(16) float xw[2 * CH * 20];      // 0.6 KB projected input
  __shared__ alignas(16) float y1[20 * Y1L];         // 12.8 KB stack1 rings
  __shared__ alignas(16) float y2[10 * Y2L];         //  3.8 KB stack2 rings
  const int w = threadIdx.x >> 6, lane = threadIdx.x & 63, b = blockIdx.x;
  if (w == 0)       stage_proj(p, b, lane, xbuf, xw);
  else if (w == 1)  pair_s1<true, true>(0, 1, p, lane, y1, xw);
  else if (w <= 10) {
    const int la = 2 * (w - 1);
    if (w & 1) pair_s1<true, false>(la, w, p, lane, y1, xw);
    else       pair_s1<false, false>(la, w, p, lane, y1, xw);
  }
  else if (w == 11) tri20<true>(p, 11, lane, y1, y2);
  else if (w == 12) tri_s2<false>(23, 12, p, lane, y2);
  else if (w == 13) tri_s2<true>(26, 13, p, lane, y2);
  else              tail29<false>(p, 14, b, lane, y2);
}

extern "C" void kernel_launch(void* const* d_in, const int* in_sizes, int n_in,
                              void* d_out, int out_size, void* d_ws, size_t ws_size,
                              hipStream_t stream) {
  (void)in_sizes; (void)out_size; (void)d_ws; (void)ws_size;
  if (n_in < 21) return;
  P p{};
  p.x  = (const float*)d_in[0];
  p.w1 = (const float*)d_in[1];    // s1_wih0 (20x64)
  p.b1 = (const float*)d_in[3];    // s1_bih0
  p.wih[0] = nullptr;              p.whh[0] = (const float*)d_in[2];
  p.bih[0] = nullptr;              p.bhh[0] = (const float*)d_in[4];
  for (int l = 1; l < 20; l++) {
    p.wih[l] = (const float*)d_in[5] + (l - 1) * 400;
    p.whh[l] = (const float*)d_in[6] + (l - 1) * 400;
    p.bih[l] = (const float*)d_in[7] + (l - 1) * 20;
    p.bhh[l] = (const float*)d_in[8] + (l - 1) * 20;
  }
  p.wih[20] = (const float*)d_in[9];   p.whh[20] = (const float*)d_in[10];
  p.bih[20] = (const float*)d_in[11];  p.bhh[20] = (const float*)d_in[12];
  for (int l = 21; l < 30; l++) {
    p.wih[l] = (const float*)d_in[13] + (l - 21) * 100;
    p.whh[l] = (const float*)d_in[14] + (l - 21) * 100;
    p.bih[l] = (const float*)d_in[15] + (l - 21) * 10;
    p.bhh[l] = (const float*)d_in[16] + (l - 21) * 10;
  }
  p.wih[30] = (const float*)d_in[17];  p.whh[30] = (const float*)d_in[18];
  p.bih[30] = (const float*)d_in[19];  p.bhh[30] = (const float*)d_in[20];
  p.out = (float*)d_out;

  rnn_fused<<<B_, 960, 0, stream>>>(p);
}

// Round 4
// 2809.356 us; speedup vs baseline: 1.9547x; 1.9547x over previous
//
#include <hip/hip_runtime.h>

#define DEVI __device__ __forceinline__
typedef float f2 __attribute__((ext_vector_type(2)));

// ---------------- problem constants ----------------
constexpr int T_ = 4096, B_ = 128;
constexpr int CH = 4, NCH = T_ / CH;   // 1024 chunks of 4 timesteps
constexpr int NSTEP2 = 1040;           // >= NCH + 16, even
constexpr int XROW = 68;               // x row padded 64->68 dwords

// One batch per workgroup. LDS strides in floats.
// y1/xw layer block: [2][CH][20] -> sl*80 + tt*20 + j
// y2 layer block:    [2][CH][12] -> sl*48 + tt*12 + j  (slots 10,11 are zero pads)
constexpr int Y1L = 160, Y2L = 96;

struct P {
  const float* x;
  const float* w1; const float* b1;    // wih0 (20x64), bih0 (20)
  const float* wih[31]; const float* whh[31];
  const float* bih[31]; const float* bhh[31];
  float* out;
};

DEVI float ftanh(float x) {
  float e = __builtin_amdgcn_exp2f(x * 2.8853900817779268f);
  return 1.0f - 2.0f * __builtin_amdgcn_rcpf(e + 1.0f);
}

DEVI f2 pfma(f2 a, f2 b, f2 c) { return __builtin_elementwise_fma(a, b, c); }

// half-dot over 10 floats (one half of a 20-dot): 5 ds_read_b64 + 5 v_pk_fma
DEVI void acc20h(f2& a, const float* r, const f2* w) {
#pragma unroll
  for (int q = 0; q < 5; q++) {
    float2 v = ((const float2*)r)[q];
    f2 t; t.x = v.x; t.y = v.y;
    a = pfma(t, w[q], a);
  }
}

// half-dot over 6 slots of a 12-slot padded row (slots 10,11 zero)
DEVI void acc12h(f2& a, const float* r, const f2* w) {
#pragma unroll
  for (int q = 0; q < 3; q++) {
    float2 v = ((const float2*)r)[q];
    f2 t; t.x = v.x; t.y = v.y;
    a = pfma(t, w[q], a);
  }
}

// combine the two lane-halves (lane j <-> lane j^32); both halves get the full sum
DEVI float redsum(f2 a, int pidx) {
  float s = a.x + a.y;
  return s + __int_as_float(__builtin_amdgcn_ds_bpermute(pidx, __float_as_int(s)));
}

// ================= wave 0: x staging + input projection =================
template <int SL>
DEVI void proj_chunk(const float* xbh, float* xww, const f2* wp, float bp,
                     bool hi, int pidx) {
#pragma unroll
  for (int tt = 0; tt < CH; tt++) {
    const float* xr = xbh + SL * (CH * XROW) + tt * XROW;
    f2 a; a.x = bp; a.y = 0.f;
#pragma unroll
    for (int q = 0; q < 8; q++) {
      float4 v = ((const float4*)xr)[q];
      union { float4 f; f2 h[2]; } u; u.f = v;
      a = pfma(u.h[0], wp[2 * q], a);
      a = pfma(u.h[1], wp[2 * q + 1], a);
    }
    const float s = redsum(a, pidx);
    if (!hi) xww[SL * 80 + tt * 20] = s;
  }
}

DEVI void stage_proj(const P& p, int b, int lane, float* xb, float* xwf) {
  const int jj = lane & 31;
  const bool act = jj < 20;
  const bool hi = lane >= 32;
  const int pidx = (lane ^ 32) << 2;
  const int j = act ? jj : 19;
  const int ko = hi ? 32 : 0;
  f2 wp[16];
#pragma unroll
  for (int k = 0; k < 16; k++) {
    wp[k].x = p.w1[j * 64 + ko + 2 * k]; wp[k].y = p.w1[j * 64 + ko + 2 * k + 1];
  }
  const float bp = hi ? 0.f : p.b1[j];
  float* xww = xwf + j;
  const float* xbh = xb + ko;

  // staging: all 64 lanes, one float4 each covers CH*64 = 256 floats
  const int tq = lane >> 4, qq = lane & 15;
  const float* src = p.x + (size_t)tq * (B_ * 64) + (size_t)b * 64 + qq * 4;
  const int dst = tq * XROW + qq * 4;
  float4 pf = *(const float4*)src;
  *(float4*)(xb + dst) = pf;
  src += CH * B_ * 64;

  for (int s = 0; s < NSTEP2; s += 2) {
    {  // phase A: c = s, slot 0
      const int c = s;
      if (c < NCH) {
        const bool more = (c + 1 < NCH);
        float4 nx;
        if (more) { nx = *(const float4*)src; src += CH * B_ * 64; }
        if (act) proj_chunk<0>(xbh, xww, wp, bp, hi, pidx);
        if (more) *(float4*)(xb + CH * XROW + dst) = nx;  // slot 1
      }
      __syncthreads();
    }
    {  // phase B: c = s+1, slot 1
      const int c = s + 1;
      if (c < NCH) {
        const bool more = (c + 1 < NCH);
        float4 nx;
        if (more) { nx = *(const float4*)src; src += CH * B_ * 64; }
        if (act) proj_chunk<1>(xbh, xww, wp, bp, hi, pidx);
        if (more) *(float4*)(xb + dst) = nx;  // slot 0
      }
      __syncthreads();
    }
  }
}

// ================= stack1 pair wave (2 layers, H=20) =================
template <int SL, bool FIRST>
DEVI void pair_chunk(const float* yin, const float* yAr, float* yAw,
                     const float* yBr, float* yBw,
                     const f2* wiA, const f2* whA, const f2* wiB, const f2* whB,
                     float bA, float bB, bool hi, int pidx) {
#pragma unroll
  for (int tt = 0; tt < CH; tt++) {
    const int IN = SL * 80 + tt * 20;
    const int PV = tt ? (SL * 80 + (tt - 1) * 20) : ((1 - SL) * 80 + 60);
    f2 a; a.x = bA; a.y = 0.f;
    if constexpr (FIRST) { const float pick = yin[IN]; if (!hi) a.x += pick; }
    else acc20h(a, yin + IN, wiA);
    acc20h(a, yAr + PV, whA);
    const float hA = ftanh(redsum(a, pidx));
    yAw[IN] = hA;                       // both halves write same value
    f2 bb; bb.x = bB; bb.y = 0.f;
    acc20h(bb, yAr + IN, wiB);          // reads row just written (same wave, DS-ordered)
    acc20h(bb, yBr + PV, whB);
    const float hB = ftanh(redsum(bb, pidx));
    yBw[IN] = hB;
  }
}

template <bool PH, bool FIRST>
DEVI void pair_s1(int la, int w, const P& p, int lane, float* y1f, float* xwf) {
  const int jj = lane & 31;
  const bool act = jj < 20;
  const bool hi = lane >= 32;
  const int pidx = (lane ^ 32) << 2;
  const int j = act ? jj : 19;
  const int ko = hi ? 10 : 0;          // term offset for this half
  const int lb = la + 1;
  f2 whA[5], whB[5], wiB[5], wiA[FIRST ? 1 : 5];
#pragma unroll
  for (int k = 0; k < 5; k++) {
    whA[k].x = p.whh[la][j * 20 + ko + 2 * k]; whA[k].y = p.whh[la][j * 20 + ko + 2 * k + 1];
    whB[k].x = p.whh[lb][j * 20 + ko + 2 * k]; whB[k].y = p.whh[lb][j * 20 + ko + 2 * k + 1];
    wiB[k].x = p.wih[lb][j * 20 + ko + 2 * k]; wiB[k].y = p.wih[lb][j * 20 + ko + 2 * k + 1];
    if constexpr (!FIRST) {
      wiA[k].x = p.wih[la][j * 20 + ko + 2 * k]; wiA[k].y = p.wih[la][j * 20 + ko + 2 * k + 1];
    }
  }
  float bA = p.bhh[la][j];
  if constexpr (!FIRST) bA += p.bih[la][j];  // L0: bih folded into projection
  float bB = p.bih[lb][j] + p.bhh[lb][j];
  if (hi) { bA = 0.f; bB = 0.f; }

  const float* yin = FIRST ? (xwf + j) : (y1f + (la - 1) * Y1L + ko);
  const float* yAr = y1f + la * Y1L + ko;
  float*       yAw = y1f + la * Y1L + j;
  const float* yBr = y1f + lb * Y1L + ko;
  float*       yBw = y1f + lb * Y1L + j;
  if (act) { yAw[140] = 0.f; yBw[140] = 0.f; }  // zero slot[1][CH-1] => drop t>0 branch

  for (int s = 0; s < NSTEP2; s += 2) {
    if ((unsigned)(s - w) < (unsigned)NCH && act)
      pair_chunk<PH ? 1 : 0, FIRST>(yin, yAr, yAw, yBr, yBw, wiA, whA, wiB, whB, bA, bB, hi, pidx);
    __syncthreads();
    if ((unsigned)(s + 1 - w) < (unsigned)NCH && act)
      pair_chunk<PH ? 0 : 1, FIRST>(yin, yAr, yAw, yBr, yBw, wiA, whA, wiB, whB, bA, bB, hi, pidx);
    __syncthreads();
  }
}

// ================= stack2 pair waves (2 layers, H=10) =================
// WIDE: first cell (L20) has a 20-wide input read from the stack-1 ring.
template <int SL, bool WIDE>
DEVI void s2pair_chunk(const float* yi0, const float* rAr, float* rAw,
                       const float* rBr, float* rBw,
                       const f2* wiA, const f2* whA, const f2* wiB, const f2* whB,
                       float bA, float bB, int pidx) {
#pragma unroll
  for (int tt = 0; tt < CH; tt++) {
    const int IN1 = SL * 80 + tt * 20;
    const int IN2 = SL * 48 + tt * 12;
    const int PV2 = tt ? (SL * 48 + (tt - 1) * 12) : ((1 - SL) * 48 + 36);
    f2 a; a.x = bA; a.y = 0.f;
    if constexpr (WIDE) acc20h(a, yi0 + IN1, wiA);
    else                acc12h(a, yi0 + IN2, wiA);
    acc12h(a, rAr + PV2, whA);
    const float hA = ftanh(redsum(a, pidx));
    rAw[IN2] = hA;
    f2 bb; bb.x = bB; bb.y = 0.f;
    acc12h(bb, rAr + IN2, wiB);         // reads row just written (same wave, DS-ordered)
    acc12h(bb, rBr + PV2, whB);
    const float hB = ftanh(redsum(bb, pidx));
    rBw[IN2] = hB;
  }
}

template <bool PH, bool WIDE>
DEVI void s2pair(int lA, int w, int rin, const P& p, int lane,
                 float* y1f, float* y2f) {
  const int jj = lane & 31;
  const bool act = jj < 10;
  const bool hi = lane >= 32;
  const int pidx = (lane ^ 32) << 2;
  const int j = act ? jj : 9;
  const int ko1 = hi ? 10 : 0;         // 20-wide input half offset (WIDE only)
  const int ko6 = hi ? 6 : 0;          // 12-slot half offset
  const int lB = lA + 1;
  f2 wiA[WIDE ? 5 : 3], whA[3], wiB[3], whB[3];
  if constexpr (WIDE) {
#pragma unroll
    for (int q = 0; q < 5; q++) {
      wiA[q].x = p.wih[lA][j * 20 + ko1 + 2 * q];
      wiA[q].y = p.wih[lA][j * 20 + ko1 + 2 * q + 1];
    }
  } else {
#pragma unroll
    for (int k = 0; k < 3; k++) {
      const int i0 = ko6 + 2 * k, i1 = i0 + 1;
      wiA[k].x = i0 < 10 ? p.wih[lA][j * 10 + i0] : 0.f;
      wiA[k].y = i1 < 10 ? p.wih[lA][j * 10 + i1] : 0.f;
    }
  }
#pragma unroll
  for (int k = 0; k < 3; k++) {
    const int i0 = ko6 + 2 * k, i1 = i0 + 1;
    whA[k].x = i0 < 10 ? p.whh[lA][j * 10 + i0] : 0.f;
    whA[k].y = i1 < 10 ? p.whh[lA][j * 10 + i1] : 0.f;
    wiB[k].x = i0 < 10 ? p.wih[lB][j * 10 + i0] : 0.f;
    wiB[k].y = i1 < 10 ? p.wih[lB][j * 10 + i1] : 0.f;
    whB[k].x = i0 < 10 ? p.whh[lB][j * 10 + i0] : 0.f;
    whB[k].y = i1 < 10 ? p.whh[lB][j * 10 + i1] : 0.f;
  }
  const float bA = hi ? 0.f : (p.bih[lA][j] + p.bhh[lA][j]);
  const float bB = hi ? 0.f : (p.bih[lB][j] + p.bhh[lB][j]);

  const int rA = lA - 20;
  const float* yi0 = WIDE ? (y1f + 19 * Y1L + ko1) : (y2f + rin * Y2L + ko6);
  const float* rAr = y2f + rA * Y2L + ko6;       float* rAw = y2f + rA * Y2L + j;
  const float* rBr = y2f + (rA + 1) * Y2L + ko6; float* rBw = y2f + (rA + 1) * Y2L + j;

  if constexpr (WIDE) {
    // zero ALL of y2 once (carry rows AND the [10],[11] pad slots read by hi
    // halves); consumers first read >= 12 barriers later, so this is race-free.
    for (int q = lane; q < 10 * Y2L; q += 64) y2f[q] = 0.f;
  }

  for (int s = 0; s < NSTEP2; s += 2) {
    if ((unsigned)(s - w) < (unsigned)NCH && act)
      s2pair_chunk<PH ? 1 : 0, WIDE>(yi0, rAr, rAw, rBr, rBw,
                                     wiA, whA, wiB, whB, bA, bB, pidx);
    __syncthreads();
    if ((unsigned)(s + 1 - w) < (unsigned)NCH && act)
      s2pair_chunk<PH ? 0 : 1, WIDE>(yi0, rAr, rAw, rBr, rBw,
                                     wiA, whA, wiB, whB, bA, bB, pidx);
    __syncthreads();
  }
}

// ================= wave 15: L28 + L29 (H=10) + L30 (H=1) + stores =========
template <int SL>
DEVI void tail3_chunk(const float* y7r, const float* y8r, float* y8w,
                      const float* y9r, float* y9w,
                      const f2* wi28, const f2* wh28, const f2* wi29,
                      const f2* wh29, const f2* wi30,
                      float b28, float b29, float b30, float wh30, float& h30,
                      float*& optr, bool st, int pidx) {
#pragma unroll
  for (int tt = 0; tt < CH; tt++) {
    const int IN2 = SL * 48 + tt * 12;
    const int PV2 = tt ? (SL * 48 + (tt - 1) * 12) : ((1 - SL) * 48 + 36);
    f2 a; a.x = b28; a.y = 0.f;
    acc12h(a, y7r + IN2, wi28);
    acc12h(a, y8r + PV2, wh28);
    const float h28 = ftanh(redsum(a, pidx));
    y8w[IN2] = h28;
    f2 c; c.x = b29; c.y = 0.f;
    acc12h(c, y8r + IN2, wi29);         // row just written (same wave, DS-ordered)
    acc12h(c, y9r + PV2, wh29);
    const float h29 = ftanh(redsum(c, pidx));
    y9w[IN2] = h29;
    f2 a3; a3.x = b30; a3.y = 0.f;
    acc12h(a3, y9r + IN2, wi30);
    const float s3 = redsum(a3, pidx);  // full dot in all act lanes
    h30 = ftanh(fmaf(h30, wh30, s3));   // all act lanes track same h30
    if (st) optr[tt * B_] = h30;
  }
  optr += CH * B_;
}

template <bool PH>
DEVI void tail3(const P& p, int w, int b, int lane, float* y2f) {
  const int jj = lane & 31;
  const bool act = jj < 10;
  const bool hi = lane >= 32;
  const int pidx = (lane ^ 32) << 2;
  const int j = act ? jj : 9;
  const int ko6 = hi ? 6 : 0;
  const bool st = (lane == 0);
  f2 wi28[3], wh28[3], wi29[3], wh29[3], wi30[3];
#pragma unroll
  for (int k = 0; k < 3; k++) {
    const int i0 = ko6 + 2 * k, i1 = i0 + 1;
    wi28[k].x = i0 < 10 ? p.wih[28][j * 10 + i0] : 0.f;
    wi28[k].y = i1 < 10 ? p.wih[28][j * 10 + i1] : 0.f;
    wh28[k].x = i0 < 10 ? p.whh[28][j * 10 + i0] : 0.f;
    wh28[k].y = i1 < 10 ? p.whh[28][j * 10 + i1] : 0.f;
    wi29[k].x = i0 < 10 ? p.wih[29][j * 10 + i0] : 0.f;
    wi29[k].y = i1 < 10 ? p.wih[29][j * 10 + i1] : 0.f;
    wh29[k].x = i0 < 10 ? p.whh[29][j * 10 + i0] : 0.f;
    wh29[k].y = i1 < 10 ? p.whh[29][j * 10 + i1] : 0.f;
    wi30[k].x = i0 < 10 ? p.wih[30][i0] : 0.f;
    wi30[k].y = i1 < 10 ? p.wih[30][i1] : 0.f;
  }
  const float b28 = hi ? 0.f : (p.bih[28][j] + p.bhh[28][j]);
  const float b29 = hi ? 0.f : (p.bih[29][j] + p.bhh[29][j]);
  const float b30 = hi ? 0.f : (p.bih[30][0] + p.bhh[30][0]);
  const float wh30 = p.whh[30][0];     // applied post-reduction, all lanes
  float h30 = 0.0f;
  const float* y7r = y2f + 7 * Y2L + ko6;
  const float* y8r = y2f + 8 * Y2L + ko6;  float* y8w = y2f + 8 * Y2L + j;
  const float* y9r = y2f + 9 * Y2L + ko6;  float* y9w = y2f + 9 * Y2L + j;
  float* optr = p.out + b;

  for (int s = 0; s < NSTEP2; s += 2) {
    if ((unsigned)(s - w) < (unsigned)NCH && act)
      tail3_chunk<PH ? 1 : 0>(y7r, y8r, y8w, y9r, y9w, wi28, wh28, wi29, wh29,
                              wi30, b28, b29, b30, wh30, h30, optr, st, pidx);
    __syncthreads();
    if ((unsigned)(s + 1 - w) < (unsigned)NCH && act)
      tail3_chunk<PH ? 0 : 1>(y7r, y8r, y8w, y9r, y9w, wi28, wh28, wi29, wh29,
                              wi30, b28, b29, b30, wh30, h30, optr, st, pidx);
    __syncthreads();
  }
  if (st) p.out[T_ * B_ + b] = h30;    // hT
}

// ================= kernel =================
// Layer -> wave map: w1..w10: stack1 pairs (L0..L19). w11: L20,21 (rows 0,1).
// w12: L22,23 (rows 2,3). w13: L24,25 (rows 4,5). w14: L26,27 (rows 6,7).
// w15: L28 (row 8) + L29 (row 9) + L30 + output stores.
__global__ __launch_bounds__(1024, 1) void rnn_fused(P p) {
  __shared__ alignas(16) float xbuf[2 * CH * XROW];  // 2.2 KB staged x
  __shared__ alignas(16) float xw[2 * CH * 20];      // 0.6 KB projected input
  __shared__ alignas(16) float y1[20 * Y1L];         // 12.8 KB stack1 rings
  __shared__ alignas(16) float y2[10 * Y2L];         //  3.8 KB stack2 rings
  const int w = threadIdx.x >> 6, lane = threadIdx.x & 63, b = blockIdx.x;
  if (w == 0)       stage_proj(p, b, lane, xbuf, xw);
  else if (w == 1)  pair_s1<true, true>(0, 1, p, lane, y1, xw);
  else if (w <= 10) {
    const int la = 2 * (w - 1);
    if (w & 1) pair_s1<true, false>(la, w, p, lane, y1, xw);
    else       pair_s1<false, false>(la, w, p, lane, y1, xw);
  }
  else if (w == 11) s2pair<true,  true >(20, 11, 0, p, lane, y1, y2);
  else if (w == 12) s2pair<false, false>(22, 12, 1, p, lane, y1, y2);
  else if (w == 13) s2pair<true,  false>(24, 13, 3, p, lane, y1, y2);
  else if (w == 14) s2pair<false, false>(26, 14, 5, p, lane, y1, y2);
  else              tail3<true>(p, 15, b, lane, y2);
}

extern "C" void kernel_launch(void* const* d_in, const int* in_sizes, int n_in,
                              void* d_out, int out_size, void* d_ws, size_t ws_size,
                              hipStream_t stream) {
  (void)in_sizes; (void)out_size; (void)d_ws; (void)ws_size;
  if (n_in < 21) return;
  P p{};
  p.x  = (const float*)d_in[0];
  p.w1 = (const float*)d_in[1];    // s1_wih0 (20x64)
  p.b1 = (const float*)d_in[3];    // s1_bih0
  p.wih[0] = nullptr;              p.whh[0] = (const float*)d_in[2];
  p.bih[0] = nullptr;              p.bhh[0] = (const float*)d_in[4];
  for (int l = 1; l < 20; l++) {
    p.wih[l] = (const float*)d_in[5] + (l - 1) * 400;
    p.whh[l] = (const float*)d_in[6] + (l - 1) * 400;
    p.bih[l] = (const float*)d_in[7] + (l - 1) * 20;
    p.bhh[l] = (const float*)d_in[8] + (l - 1) * 20;
  }
  p.wih[20] = (const float*)d_in[9];   p.whh[20] = (const float*)d_in[10];
  p.bih[20] = (const float*)d_in[11];  p.bhh[20] = (const float*)d_in[12];
  for (int l = 21; l < 30; l++) {
    p.wih[l] = (const float*)d_in[13] + (l - 21) * 100;
    p.whh[l] = (const float*)d_in[14] + (l - 21) * 100;
    p.bih[l] = (const float*)d_in[15] + (l - 21) * 10;
    p.bhh[l] = (const float*)d_in[16] + (l - 21) * 10;
  }
  p.wih[30] = (const float*)d_in[17];  p.whh[30] = (const float*)d_in[18];
  p.bih[30] = (const float*)d_in[19];  p.bhh[30] = (const float*)d_in[20];
  p.out = (float*)d_out;

  rnn_fused<<<B_, 1024, 0, stream>>>(p);
}

// Round 5
// 2090.932 us; speedup vs baseline: 2.6264x; 1.3436x over previous
//
#include <hip/hip_runtime.h>

#define DEVI __device__ __forceinline__
typedef float f2 __attribute__((ext_vector_type(2)));
typedef unsigned u32x2 __attribute__((ext_vector_type(2)));

// ---------------- problem constants ----------------
constexpr int T_ = 4096, B_ = 128;
constexpr int CH = 4, NCH = T_ / CH;   // 1024 chunks of 4 timesteps
constexpr int NSTEP2 = 1040;           // >= NCH + 16, even
constexpr int XROW = 68;               // x row padded 64->68 dwords

// One batch per workgroup. LDS strides in floats.
// y1/xw layer block: [2][CH][20] -> sl*80 + tt*20 + j
// y2 layer block:    [2][CH][12] -> sl*48 + tt*12 + j  (slots 10,11 are zero pads)
constexpr int Y1L = 160, Y2L = 96;

struct P {
  const float* x;
  const float* w1; const float* b1;    // wih0 (20x64), bih0 (20)
  const float* wih[31]; const float* whh[31];
  const float* bih[31]; const float* bhh[31];
  float* out;
};

DEVI float ftanh(float x) {
  float e = __builtin_amdgcn_exp2f(x * 2.8853900817779268f);
  return 1.0f - 2.0f * __builtin_amdgcn_rcpf(e + 1.0f);
}

DEVI f2 pfma(f2 a, f2 b, f2 c) { return __builtin_elementwise_fma(a, b, c); }

// half-dot over 10 floats (one half of a 20-dot): 5 ds_read_b64 + 5 v_pk_fma
DEVI void acc20h(f2& a, const float* r, const f2* w) {
#pragma unroll
  for (int q = 0; q < 5; q++) {
    float2 v = ((const float2*)r)[q];
    f2 t; t.x = v.x; t.y = v.y;
    a = pfma(t, w[q], a);
  }
}

// half-dot over 6 slots of a 12-slot padded row (slots 10,11 zero)
DEVI void acc12h(f2& a, const float* r, const f2* w) {
#pragma unroll
  for (int q = 0; q < 3; q++) {
    float2 v = ((const float2*)r)[q];
    f2 t; t.x = v.x; t.y = v.y;
    a = pfma(t, w[q], a);
  }
}

// full dot over 10 floats of a 12-padded row (off-chain, any lane): 2 b128 + 1 b64
DEVI float dot10(const float* r, const f2* w) {
  float4 v0 = ((const float4*)r)[0];
  float4 v1 = ((const float4*)r)[1];
  float2 v2 = *(const float2*)(r + 8);
  union { float4 f; f2 h[2]; } u0, u1; u0.f = v0; u1.f = v1;
  f2 a0{0.f, 0.f}, a1{0.f, 0.f};
  a0 = pfma(u0.h[0], w[0], a0);
  a1 = pfma(u0.h[1], w[1], a1);
  a0 = pfma(u1.h[0], w[2], a0);
  a1 = pfma(u1.h[1], w[3], a1);
  f2 t; t.x = v2.x; t.y = v2.y;
  a0 = pfma(t, w[4], a0);
  f2 s = a0 + a1;
  return s.x + s.y;
}

// combine the two lane-halves (lane j <-> lane j^32) via v_permlane32_swap_b32
// (VALU-class, off the LDS pipe). {r.x,r.y} = halves exchanged; r.x + r.y ==
// s[lane] + s[lane^32] in EVERY lane, so both halves get the full sum.
DEVI float redsum(f2 a) {
  const float s = a.x + a.y;
  u32x2 r = __builtin_amdgcn_permlane32_swap(__float_as_uint(s),
                                             __float_as_uint(s), false, false);
  return __uint_as_float(r.x) + __uint_as_float(r.y);
}

// ================= wave 0: x staging + input projection + L30 + stores ====
template <int SL>
DEVI void proj_chunk(const float* xbh, float* xww, const f2* wp, float bp,
                     bool hi) {
#pragma unroll
  for (int tt = 0; tt < CH; tt++) {
    const float* xr = xbh + SL * (CH * XROW) + tt * XROW;
    f2 a; a.x = bp; a.y = 0.f;
#pragma unroll
    for (int q = 0; q < 8; q++) {
      float4 v = ((const float4*)xr)[q];
      union { float4 f; f2 h[2]; } u; u.f = v;
      a = pfma(u.h[0], wp[2 * q], a);
      a = pfma(u.h[1], wp[2 * q + 1], a);
    }
    const float s = redsum(a);
    if (!hi) xww[SL * 80 + tt * 20] = s;
  }
}

// L30 (H=1): off-chain dot over L29's ring row + tiny scalar recurrence.
// All lanes compute redundantly (uniform); lane 0 stores.
template <int SL>
DEVI void l30_chunk(const float* y29, const f2* wi30, float b30, float wh30,
                    float& h30, float*& optr, bool st) {
#pragma unroll
  for (int tt = 0; tt < CH; tt++) {
    const float d = dot10(y29 + SL * 48 + tt * 12, wi30);
    h30 = ftanh(fmaf(h30, wh30, d + b30));
    if (st) optr[tt * B_] = h30;
  }
  optr += CH * B_;
}

DEVI void stage_proj(const P& p, int b, int lane, float* xb, float* xwf,
                     const float* y29) {
  const int jj = lane & 31;
  const bool act = jj < 20;
  const bool hi = lane >= 32;
  const int j = act ? jj : 19;
  const int ko = hi ? 32 : 0;
  f2 wp[16];
#pragma unroll
  for (int k = 0; k < 16; k++) {
    wp[k].x = p.w1[j * 64 + ko + 2 * k]; wp[k].y = p.w1[j * 64 + ko + 2 * k + 1];
  }
  const float bp = hi ? 0.f : p.b1[j];
  float* xww = xwf + j;
  const float* xbh = xb + ko;

  // L30 state
  f2 wi30[5];
#pragma unroll
  for (int k = 0; k < 5; k++) {
    wi30[k].x = p.wih[30][2 * k];
    wi30[k].y = p.wih[30][2 * k + 1];
  }
  const float b30 = p.bih[30][0] + p.bhh[30][0];
  const float wh30 = p.whh[30][0];
  float h30 = 0.f;
  float* optr = p.out + b;
  const bool st = (lane == 0);

  // staging: all 64 lanes, one float4 each covers CH*64 = 256 floats
  const int tq = lane >> 4, qq = lane & 15;
  const float* src = p.x + (size_t)tq * (B_ * 64) + (size_t)b * 64 + qq * 4;
  const int dst = tq * XROW + qq * 4;
  float4 pf = *(const float4*)src;
  *(float4*)(xb + dst) = pf;
  src += CH * B_ * 64;

  for (int s = 0; s < NSTEP2; s += 2) {
    {  // phase A: proj chunk c = s (slot 0), L30 chunk c = s-16 (slot 0)
      const int c = s;
      if (c < NCH) {
        const bool more = (c + 1 < NCH);
        float4 nx;
        if (more) { nx = *(const float4*)src; src += CH * B_ * 64; }
        if (act) proj_chunk<0>(xbh, xww, wp, bp, hi);
        if (more) *(float4*)(xb + CH * XROW + dst) = nx;  // slot 1
      }
      if ((unsigned)(s - 16) < (unsigned)NCH)
        l30_chunk<0>(y29, wi30, b30, wh30, h30, optr, st);
      __syncthreads();
    }
    {  // phase B: proj chunk c = s+1 (slot 1), L30 chunk c = s-15 (slot 1)
      const int c = s + 1;
      if (c < NCH) {
        const bool more = (c + 1 < NCH);
        float4 nx;
        if (more) { nx = *(const float4*)src; src += CH * B_ * 64; }
        if (act) proj_chunk<1>(xbh, xww, wp, bp, hi);
        if (more) *(float4*)(xb + dst) = nx;  // slot 0
      }
      if ((unsigned)(s + 1 - 16) < (unsigned)NCH)
        l30_chunk<1>(y29, wi30, b30, wh30, h30, optr, st);
      __syncthreads();
    }
  }
  if (st) p.out[T_ * B_ + b] = h30;  // hT
}

// ================= stack1 pair wave (2 layers, H=20) =================
template <int SL, bool FIRST>
DEVI void pair_chunk(const float* yin, const float* yAr, float* yAw,
                     const float* yBr, float* yBw,
                     const f2* wiA, const f2* whA, const f2* wiB, const f2* whB,
                     float bA, float bB, bool hi) {
#pragma unroll
  for (int tt = 0; tt < CH; tt++) {
    const int IN = SL * 80 + tt * 20;
    const int PV = tt ? (SL * 80 + (tt - 1) * 20) : ((1 - SL) * 80 + 60);
    f2 a; a.x = bA; a.y = 0.f;
    if constexpr (FIRST) { const float pick = yin[IN]; if (!hi) a.x += pick; }
    else acc20h(a, yin + IN, wiA);
    acc20h(a, yAr + PV, whA);
    const float hA = ftanh(redsum(a));
    yAw[IN] = hA;                       // both halves write same value
    f2 bb; bb.x = bB; bb.y = 0.f;
    acc20h(bb, yAr + IN, wiB);          // reads row just written (same wave, DS-ordered)
    acc20h(bb, yBr + PV, whB);
    const float hB = ftanh(redsum(bb));
    yBw[IN] = hB;
  }
}

template <bool PH, bool FIRST>
DEVI void pair_s1(int la, int w, const P& p, int lane, float* y1f, float* xwf) {
  const int jj = lane & 31;
  const bool act = jj < 20;
  const bool hi = lane >= 32;
  const int j = act ? jj : 19;
  const int ko = hi ? 10 : 0;          // term offset for this half
  const int lb = la + 1;
  f2 whA[5], whB[5], wiB[5], wiA[FIRST ? 1 : 5];
#pragma unroll
  for (int k = 0; k < 5; k++) {
    whA[k].x = p.whh[la][j * 20 + ko + 2 * k]; whA[k].y = p.whh[la][j * 20 + ko + 2 * k + 1];
    whB[k].x = p.whh[lb][j * 20 + ko + 2 * k]; whB[k].y = p.whh[lb][j * 20 + ko + 2 * k + 1];
    wiB[k].x = p.wih[lb][j * 20 + ko + 2 * k]; wiB[k].y = p.wih[lb][j * 20 + ko + 2 * k + 1];
    if constexpr (!FIRST) {
      wiA[k].x = p.wih[la][j * 20 + ko + 2 * k]; wiA[k].y = p.wih[la][j * 20 + ko + 2 * k + 1];
    }
  }
  float bA = p.bhh[la][j];
  if constexpr (!FIRST) bA += p.bih[la][j];  // L0: bih folded into projection
  float bB = p.bih[lb][j] + p.bhh[lb][j];
  if (hi) { bA = 0.f; bB = 0.f; }

  const float* yin = FIRST ? (xwf + j) : (y1f + (la - 1) * Y1L + ko);
  const float* yAr = y1f + la * Y1L + ko;
  float*       yAw = y1f + la * Y1L + j;
  const float* yBr = y1f + lb * Y1L + ko;
  float*       yBw = y1f + lb * Y1L + j;
  if (act) { yAw[140] = 0.f; yBw[140] = 0.f; }  // zero slot[1][CH-1] => drop t>0 branch

  for (int s = 0; s < NSTEP2; s += 2) {
    if ((unsigned)(s - w) < (unsigned)NCH && act)
      pair_chunk<PH ? 1 : 0, FIRST>(yin, yAr, yAw, yBr, yBw, wiA, whA, wiB, whB, bA, bB, hi);
    __syncthreads();
    if ((unsigned)(s + 1 - w) < (unsigned)NCH && act)
      pair_chunk<PH ? 0 : 1, FIRST>(yin, yAr, yAw, yBr, yBw, wiA, whA, wiB, whB, bA, bB, hi);
    __syncthreads();
  }
}

// ================= stack2 pair waves (2 layers, H=10) =================
// WIDE: first cell (L20) has a 20-wide input read from the stack-1 ring.
template <int SL, bool WIDE>
DEVI void s2pair_chunk(const float* yi0, const float* rAr, float* rAw,
                       const float* rBr, float* rBw,
                       const f2* wiA, const f2* whA, const f2* wiB, const f2* whB,
                       float bA, float bB) {
#pragma unroll
  for (int tt = 0; tt < CH; tt++) {
    const int IN1 = SL * 80 + tt * 20;
    const int IN2 = SL * 48 + tt * 12;
    const int PV2 = tt ? (SL * 48 + (tt - 1) * 12) : ((1 - SL) * 48 + 36);
    f2 a; a.x = bA; a.y = 0.f;
    if constexpr (WIDE) acc20h(a, yi0 + IN1, wiA);
    else                acc12h(a, yi0 + IN2, wiA);
    acc12h(a, rAr + PV2, whA);
    const float hA = ftanh(redsum(a));
    rAw[IN2] = hA;
    f2 bb; bb.x = bB; bb.y = 0.f;
    acc12h(bb, rAr + IN2, wiB);         // reads row just written (same wave, DS-ordered)
    acc12h(bb, rBr + PV2, whB);
    const float hB = ftanh(redsum(bb));
    rBw[IN2] = hB;
  }
}

template <bool PH, bool WIDE>
DEVI void s2pair(int lA, int w, int rin, const P& p, int lane,
                 float* y1f, float* y2f) {
  const int jj = lane & 31;
  const bool act = jj < 10;
  const bool hi = lane >= 32;
  const int j = act ? jj : 9;
  const int ko1 = hi ? 10 : 0;         // 20-wide input half offset (WIDE only)
  const int ko6 = hi ? 6 : 0;          // 12-slot half offset
  const int lB = lA + 1;
  f2 wiA[WIDE ? 5 : 3], whA[3], wiB[3], whB[3];
  if constexpr (WIDE) {
#pragma unroll
    for (int q = 0; q < 5; q++) {
      wiA[q].x = p.wih[lA][j * 20 + ko1 + 2 * q];
      wiA[q].y = p.wih[lA][j * 20 + ko1 + 2 * q + 1];
    }
  } else {
#pragma unroll
    for (int k = 0; k < 3; k++) {
      const int i0 = ko6 + 2 * k, i1 = i0 + 1;
      wiA[k].x = i0 < 10 ? p.wih[lA][j * 10 + i0] : 0.f;
      wiA[k].y = i1 < 10 ? p.wih[lA][j * 10 + i1] : 0.f;
    }
  }
#pragma unroll
  for (int k = 0; k < 3; k++) {
    const int i0 = ko6 + 2 * k, i1 = i0 + 1;
    whA[k].x = i0 < 10 ? p.whh[lA][j * 10 + i0] : 0.f;
    whA[k].y = i1 < 10 ? p.whh[lA][j * 10 + i1] : 0.f;
    wiB[k].x = i0 < 10 ? p.wih[lB][j * 10 + i0] : 0.f;
    wiB[k].y = i1 < 10 ? p.wih[lB][j * 10 + i1] : 0.f;
    whB[k].x = i0 < 10 ? p.whh[lB][j * 10 + i0] : 0.f;
    whB[k].y = i1 < 10 ? p.whh[lB][j * 10 + i1] : 0.f;
  }
  const float bA = hi ? 0.f : (p.bih[lA][j] + p.bhh[lA][j]);
  const float bB = hi ? 0.f : (p.bih[lB][j] + p.bhh[lB][j]);

  const int rA = lA - 20;
  const float* yi0 = WIDE ? (y1f + 19 * Y1L + ko1) : (y2f + rin * Y2L + ko6);
  const float* rAr = y2f + rA * Y2L + ko6;       float* rAw = y2f + rA * Y2L + j;
  const float* rBr = y2f + (rA + 1) * Y2L + ko6; float* rBw = y2f + (rA + 1) * Y2L + j;

  if constexpr (WIDE) {
    // zero ALL of y2 once (carry rows AND the [10],[11] pad slots read by hi
    // halves); consumers first read >= 12 barriers later, so this is race-free.
    for (int q = lane; q < 10 * Y2L; q += 64) y2f[q] = 0.f;
  }

  for (int s = 0; s < NSTEP2; s += 2) {
    if ((unsigned)(s - w) < (unsigned)NCH && act)
      s2pair_chunk<PH ? 1 : 0, WIDE>(yi0, rAr, rAw, rBr, rBw,
                                     wiA, whA, wiB, whB, bA, bB);
    __syncthreads();
    if ((unsigned)(s + 1 - w) < (unsigned)NCH && act)
      s2pair_chunk<PH ? 0 : 1, WIDE>(yi0, rAr, rAw, rBr, rBw,
                                     wiA, whA, wiB, whB, bA, bB);
    __syncthreads();
  }
}

// ================= kernel =================
// Layer -> wave map: w0: staging + proj + L30 + stores (skew 16).
// w1..w10: stack1 pairs (L0..L19). w11: L20,21 (rows 0,1, WIDE).
// w12: L22,23 (rows 2,3). w13: L24,25 (rows 4,5). w14: L26,27 (rows 6,7).
// w15: L28,29 (rows 8,9). Max serial chain per wave: 2 cells/timestep.
__global__ __launch_bounds__(1024, 1) void rnn_fused(P p) {
  __shared__ alignas(16) float xbuf[2 * CH * XROW];  // 2.2 KB staged x
  __shared__ alignas(16) float xw[2 * CH * 20];      // 0.6 KB projected input
  __shared__ alignas(16) float y1[20 * Y1L];         // 12.8 KB stack1 rings
  __shared__ alignas(16) float y2[10 * Y2L];         //  3.8 KB stack2 rings
  const int w = threadIdx.x >> 6, lane = threadIdx.x & 63, b = blockIdx.x;
  if (w == 0)       stage_proj(p, b, lane, xbuf, xw, y2 + 9 * Y2L);
  else if (w == 1)  pair_s1<true, true>(0, 1, p, lane, y1, xw);
  else if (w <= 10) {
    const int la = 2 * (w - 1);
    if (w & 1) pair_s1<true, false>(la, w, p, lane, y1, xw);
    else       pair_s1<false, false>(la, w, p, lane, y1, xw);
  }
  else if (w == 11) s2pair<true,  true >(20, 11, 0, p, lane, y1, y2);
  else if (w == 12) s2pair<false, false>(22, 12, 1, p, lane, y1, y2);
  else if (w == 13) s2pair<true,  false>(24, 13, 3, p, lane, y1, y2);
  else if (w == 14) s2pair<false, false>(26, 14, 5, p, lane, y1, y2);
  else              s2pair<true,  false>(28, 15, 7, p, lane, y1, y2);
}

extern "C" void kernel_launch(void* const* d_in, const int* in_sizes, int n_in,
                              void* d_out, int out_size, void* d_ws, size_t ws_size,
                              hipStream_t stream) {
  (void)in_sizes; (void)out_size; (void)d_ws; (void)ws_size;
  if (n_in < 21) return;
  P p{};
  p.x  = (const float*)d_in[0];
  p.w1 = (const float*)d_in[1];    // s1_wih0 (20x64)
  p.b1 = (const float*)d_in[3];    // s1_bih0
  p.wih[0] = nullptr;              p.whh[0] = (const float*)d_in[2];
  p.bih[0] = nullptr;              p.bhh[0] = (const float*)d_in[4];
  for (int l = 1; l < 20; l++) {
    p.wih[l] = (const float*)d_in[5] + (l - 1) * 400;
    p.whh[l] = (const float*)d_in[6] + (l - 1) * 400;
    p.bih[l] = (const float*)d_in[7] + (l - 1) * 20;
    p.bhh[l] = (const float*)d_in[8] + (l - 1) * 20;
  }
  p.wih[20] = (const float*)d_in[9];   p.whh[20] = (const float*)d_in[10];
  p.bih[20] = (const float*)d_in[11];  p.bhh[20] = (const float*)d_in[12];
  for (int l = 21; l < 30; l++) {
    p.wih[l] = (const float*)d_in[13] + (l - 21) * 100;
    p.whh[l] = (const float*)d_in[14] + (l - 21) * 100;
    p.bih[l] = (const float*)d_in[15] + (l - 21) * 10;
    p.bhh[l] = (const float*)d_in[16] + (l - 21) * 10;
  }
  p.wih[30] = (const float*)d_in[17];  p.whh[30] = (const float*)d_in[18];
  p.bih[30] = (const float*)d_in[19];  p.bhh[30] = (const float*)d_in[20];
  p.out = (float*)d_out;

  rnn_fused<<<B_, 1024, 0, stream>>>(p);
}

// Round 6
// 1646.119 us; speedup vs baseline: 3.3361x; 1.2702x over previous
//
#include <hip/hip_runtime.h>

#define DEVI __device__ __forceinline__
typedef float f2 __attribute__((ext_vector_type(2)));
typedef unsigned u32x2 __attribute__((ext_vector_type(2)));

// ---------------- problem constants ----------------
constexpr int T_ = 4096, B_ = 128;
constexpr int CH = 8, NCH = T_ / CH;   // 512 chunks of 8 timesteps
constexpr int NSTEP2 = 528;            // >= NCH + 16, even
constexpr int XROW = 68;               // x row padded 64->68 dwords

// One batch per workgroup. LDS strides in floats.
// y1/xw layer block: [2][CH][20] -> sl*CH*20 + tt*20 + j
// y2 layer block:    [2][CH][12] -> sl*CH*12 + tt*12 + j (slots 10,11 zero pads)
constexpr int Y1L = 2 * CH * 20;       // 320
constexpr int Y2L = 2 * CH * 12;       // 192

struct P {
  const float* x;
  const float* w1; const float* b1;    // wih0 (20x64), bih0 (20)
  const float* wih[31]; const float* whh[31];
  const float* bih[31]; const float* bhh[31];
  float* out;
};

DEVI float ftanh(float x) {
  float e = __builtin_amdgcn_exp2f(x * 2.8853900817779268f);
  return 1.0f - 2.0f * __builtin_amdgcn_rcpf(e + 1.0f);
}

DEVI f2 pfma(f2 a, f2 b, f2 c) { return __builtin_elementwise_fma(a, b, c); }

// uniform half-dot over 10 floats of a 20-row: 2 ds_read_b128 + 1 ds_read_b64.
// r128 = rowbase + (hi?12:0), r64 = rowbase + (hi?10:8); weights pre-reordered.
DEVI void acc20u(f2& a, const float* r128, const float* r64, const f2* w) {
  float4 v0 = ((const float4*)r128)[0];
  float4 v1 = ((const float4*)r128)[1];
  float2 v2 = *(const float2*)r64;
  union { float4 f; f2 h[2]; } u0, u1; u0.f = v0; u1.f = v1;
  f2 t; t.x = v2.x; t.y = v2.y;
  a = pfma(u0.h[0], w[0], a);
  a = pfma(u0.h[1], w[1], a);
  a = pfma(u1.h[0], w[2], a);
  a = pfma(u1.h[1], w[3], a);
  a = pfma(t, w[4], a);
}

// uniform half-dot over 6 slots of a 12-row: 1 b128 + 1 b64.
// r128 = rowbase + (hi?8:0), r64 = rowbase + (hi?6:4); weights pre-reordered.
DEVI void acc12u(f2& a, const float* r128, const float* r64, const f2* w) {
  float4 v0 = *(const float4*)r128;
  float2 v2 = *(const float2*)r64;
  union { float4 f; f2 h[2]; } u; u.f = v0;
  f2 t; t.x = v2.x; t.y = v2.y;
  a = pfma(u.h[0], w[0], a);
  a = pfma(u.h[1], w[1], a);
  a = pfma(t, w[2], a);
}

// full dot over 10 floats of a 12-padded row (off-chain, uniform): 2 b128 + 1 b64
DEVI float dot10(const float* r, const f2* w) {
  float4 v0 = ((const float4*)r)[0];
  float4 v1 = ((const float4*)r)[1];
  float2 v2 = *(const float2*)(r + 8);
  union { float4 f; f2 h[2]; } u0, u1; u0.f = v0; u1.f = v1;
  f2 a0{0.f, 0.f}, a1{0.f, 0.f};
  a0 = pfma(u0.h[0], w[0], a0);
  a1 = pfma(u0.h[1], w[1], a1);
  a0 = pfma(u1.h[0], w[2], a0);
  a1 = pfma(u1.h[1], w[3], a1);
  f2 t; t.x = v2.x; t.y = v2.y;
  a0 = pfma(t, w[4], a0);
  f2 s = a0 + a1;
  return s.x + s.y;
}

// combine the two lane-halves (lane j <-> lane j^32) via v_permlane32_swap_b32
// (VALU-class, off the LDS pipe). r.x + r.y == s[lane] + s[lane^32] in EVERY
// lane, so both halves get the full sum.
DEVI float redsum(f2 a) {
  const float s = a.x + a.y;
  u32x2 r = __builtin_amdgcn_permlane32_swap(__float_as_uint(s),
                                             __float_as_uint(s), false, false);
  return __uint_as_float(r.x) + __uint_as_float(r.y);
}

// ================= wave 0: x staging + input projection + L30 + stores ====
template <int SL>
DEVI void proj_chunk(const float* xbh, float* xww, const f2* wp, float bp,
                     bool hi) {
#pragma unroll
  for (int tt = 0; tt < CH; tt++) {
    const float* xr = xbh + SL * (CH * XROW) + tt * XROW;
    f2 a; a.x = bp; a.y = 0.f;
#pragma unroll
    for (int q = 0; q < 8; q++) {
      float4 v = ((const float4*)xr)[q];
      union { float4 f; f2 h[2]; } u; u.f = v;
      a = pfma(u.h[0], wp[2 * q], a);
      a = pfma(u.h[1], wp[2 * q + 1], a);
    }
    const float s = redsum(a);
    if (!hi) xww[SL * (CH * 20) + tt * 20] = s;
  }
}

// L30 (H=1): off-chain dot over L29's ring row + tiny scalar recurrence.
template <int SL>
DEVI void l30_chunk(const float* y29, const f2* wi30, float b30, float wh30,
                    float& h30, float*& optr, bool st) {
#pragma unroll
  for (int tt = 0; tt < CH; tt++) {
    const float d = dot10(y29 + SL * (CH * 12) + tt * 12, wi30);
    h30 = ftanh(fmaf(h30, wh30, d + b30));
    if (st) optr[tt * B_] = h30;
  }
  optr += CH * B_;
}

DEVI void stage_proj(const P& p, int b, int lane, float* xb, float* xwf,
                     const float* y29) {
  const int jj = lane & 31;
  const bool act = jj < 20;
  const bool hi = lane >= 32;
  const int j = act ? jj : 19;
  const int ko = hi ? 32 : 0;
  f2 wp[16];
#pragma unroll
  for (int k = 0; k < 16; k++) {
    wp[k].x = p.w1[j * 64 + ko + 2 * k]; wp[k].y = p.w1[j * 64 + ko + 2 * k + 1];
  }
  const float bp = hi ? 0.f : p.b1[j];
  float* xww = xwf + j;
  const float* xbh = xb + ko;

  // L30 state
  f2 wi30[5];
#pragma unroll
  for (int k = 0; k < 5; k++) {
    wi30[k].x = p.wih[30][2 * k];
    wi30[k].y = p.wih[30][2 * k + 1];
  }
  const float b30 = p.bih[30][0] + p.bhh[30][0];
  const float wh30 = p.whh[30][0];
  float h30 = 0.f;
  float* optr = p.out + b;
  const bool st = (lane == 0);

  // staging: 64 lanes x 2 float4 each covers CH*64 = 512 floats per chunk
  const int tq = lane >> 4, qq = lane & 15;
  const float* src[2]; int dst[2];
#pragma unroll
  for (int r = 0; r < 2; r++) {
    const int row = r * 4 + tq;          // 0..7
    src[r] = p.x + (size_t)row * (B_ * 64) + (size_t)b * 64 + qq * 4;
    dst[r] = row * XROW + qq * 4;
  }
  float4 pf[2];
#pragma unroll
  for (int r = 0; r < 2; r++) pf[r] = *(const float4*)src[r];
#pragma unroll
  for (int r = 0; r < 2; r++) *(float4*)(xb + dst[r]) = pf[r];
#pragma unroll
  for (int r = 0; r < 2; r++) src[r] += CH * B_ * 64;

  for (int s = 0; s < NSTEP2; s += 2) {
    {  // phase A: proj chunk c = s (slot 0), L30 chunk c = s-16 (slot 0)
      const int c = s;
      if (c < NCH) {
        const bool more = (c + 1 < NCH);
        float4 nx[2];
        if (more) {
#pragma unroll
          for (int r = 0; r < 2; r++) { nx[r] = *(const float4*)src[r]; src[r] += CH * B_ * 64; }
        }
        if (act) proj_chunk<0>(xbh, xww, wp, bp, hi);
        if (more) {
#pragma unroll
          for (int r = 0; r < 2; r++) *(float4*)(xb + CH * XROW + dst[r]) = nx[r];  // slot 1
        }
      }
      if ((unsigned)(s - 16) < (unsigned)NCH)
        l30_chunk<0>(y29, wi30, b30, wh30, h30, optr, st);
      __syncthreads();
    }
    {  // phase B: proj chunk c = s+1 (slot 1), L30 chunk c = s-15 (slot 1)
      const int c = s + 1;
      if (c < NCH) {
        const bool more = (c + 1 < NCH);
        float4 nx[2];
        if (more) {
#pragma unroll
          for (int r = 0; r < 2; r++) { nx[r] = *(const float4*)src[r]; src[r] += CH * B_ * 64; }
        }
        if (act) proj_chunk<1>(xbh, xww, wp, bp, hi);
        if (more) {
#pragma unroll
          for (int r = 0; r < 2; r++) *(float4*)(xb + dst[r]) = nx[r];  // slot 0
        }
      }
      if ((unsigned)(s + 1 - 16) < (unsigned)NCH)
        l30_chunk<1>(y29, wi30, b30, wh30, h30, optr, st);
      __syncthreads();
    }
  }
  if (st) p.out[T_ * B_ + b] = h30;  // hT
}

// ================= stack1 pair wave (2 layers, H=20) =================
template <int SL, bool FIRST>
DEVI void pair_chunk(const float* yin, const float* yinB,
                     const float* yArA, const float* yArB, float* yAw,
                     const float* yBrA, const float* yBrB, float* yBw,
                     const f2* wiA, const f2* whA, const f2* wiB, const f2* whB,
                     float bA, float bB, bool hi) {
#pragma unroll
  for (int tt = 0; tt < CH; tt++) {
    const int IN = SL * (CH * 20) + tt * 20;
    const int PV = tt ? (IN - 20) : ((1 - SL) * (CH * 20) + (CH - 1) * 20);
    f2 a; a.x = bA; a.y = 0.f;
    if constexpr (FIRST) { const float pick = yin[IN]; if (!hi) a.x += pick; }
    else acc20u(a, yin + IN, yinB + IN, wiA);
    acc20u(a, yArA + PV, yArB + PV, whA);
    const float hA = ftanh(redsum(a));
    yAw[IN] = hA;                       // both halves write same value
    f2 bb; bb.x = bB; bb.y = 0.f;
    acc20u(bb, yArA + IN, yArB + IN, wiB);  // row just written (same wave, DS-ordered)
    acc20u(bb, yBrA + PV, yBrB + PV, whB);
    const float hB = ftanh(redsum(bb));
    yBw[IN] = hB;
  }
}

template <bool PH, bool FIRST>
DEVI void pair_s1(int la, int w, const P& p, int lane, float* y1f, float* xwf) {
  const int jj = lane & 31;
  const bool act = jj < 20;
  const bool hi = lane >= 32;
  const int j = act ? jj : 19;
  const int o128 = hi ? 12 : 0, o64 = hi ? 10 : 8;
  const int lb = la + 1;
  f2 whA[5], whB[5], wiB[5], wiA[FIRST ? 1 : 5];
#pragma unroll
  for (int q = 0; q < 5; q++) {
    const int tb = hi ? (q < 4 ? 12 + 2 * q : 10) : 2 * q;  // read-order term base
    whA[q].x = p.whh[la][j * 20 + tb]; whA[q].y = p.whh[la][j * 20 + tb + 1];
    whB[q].x = p.whh[lb][j * 20 + tb]; whB[q].y = p.whh[lb][j * 20 + tb + 1];
    wiB[q].x = p.wih[lb][j * 20 + tb]; wiB[q].y = p.wih[lb][j * 20 + tb + 1];
    if constexpr (!FIRST) {
      wiA[q].x = p.wih[la][j * 20 + tb]; wiA[q].y = p.wih[la][j * 20 + tb + 1];
    }
  }
  float bA = p.bhh[la][j];
  if constexpr (!FIRST) bA += p.bih[la][j];  // L0: bih folded into projection
  float bB = p.bih[lb][j] + p.bhh[lb][j];
  if (hi) { bA = 0.f; bB = 0.f; }

  const float* yin  = FIRST ? (xwf + j) : (y1f + (la - 1) * Y1L + o128);
  const float* yinB = FIRST ? nullptr   : (y1f + (la - 1) * Y1L + o64);
  const float* yArA = y1f + la * Y1L + o128;
  const float* yArB = y1f + la * Y1L + o64;
  float*       yAw  = y1f + la * Y1L + j;
  const float* yBrA = y1f + lb * Y1L + o128;
  const float* yBrB = y1f + lb * Y1L + o64;
  float*       yBw  = y1f + lb * Y1L + j;
  if (act) { yAw[(2 * CH - 1) * 20] = 0.f; yBw[(2 * CH - 1) * 20] = 0.f; }  // h(-1)=0

  for (int s = 0; s < NSTEP2; s += 2) {
    if ((unsigned)(s - w) < (unsigned)NCH && act)
      pair_chunk<PH ? 1 : 0, FIRST>(yin, yinB, yArA, yArB, yAw, yBrA, yBrB, yBw,
                                    wiA, whA, wiB, whB, bA, bB, hi);
    __syncthreads();
    if ((unsigned)(s + 1 - w) < (unsigned)NCH && act)
      pair_chunk<PH ? 0 : 1, FIRST>(yin, yinB, yArA, yArB, yAw, yBrA, yBrB, yBw,
                                    wiA, whA, wiB, whB, bA, bB, hi);
    __syncthreads();
  }
}

// ================= stack2 pair waves (2 layers, H=10) =================
// WIDE: first cell (L20) has a 20-wide input read from the stack-1 ring.
template <int SL, bool WIDE>
DEVI void s2pair_chunk(const float* yi0A, const float* yi0B,
                       const float* rArA, const float* rArB, float* rAw,
                       const float* rBrA, const float* rBrB, float* rBw,
                       const f2* wiA, const f2* whA, const f2* wiB, const f2* whB,
                       float bA, float bB) {
#pragma unroll
  for (int tt = 0; tt < CH; tt++) {
    const int IN1 = SL * (CH * 20) + tt * 20;
    const int IN2 = SL * (CH * 12) + tt * 12;
    const int PV2 = tt ? (IN2 - 12) : ((1 - SL) * (CH * 12) + (CH - 1) * 12);
    f2 a; a.x = bA; a.y = 0.f;
    if constexpr (WIDE) acc20u(a, yi0A + IN1, yi0B + IN1, wiA);
    else                acc12u(a, yi0A + IN2, yi0B + IN2, wiA);
    acc12u(a, rArA + PV2, rArB + PV2, whA);
    const float hA = ftanh(redsum(a));
    rAw[IN2] = hA;
    f2 bb; bb.x = bB; bb.y = 0.f;
    acc12u(bb, rArA + IN2, rArB + IN2, wiB);  // row just written (same wave, DS-ordered)
    acc12u(bb, rBrA + PV2, rBrB + PV2, whB);
    const float hB = ftanh(redsum(bb));
    rBw[IN2] = hB;
  }
}

template <bool PH, bool WIDE>
DEVI void s2pair(int lA, int w, int rin, const P& p, int lane,
                 float* y1f, float* y2f) {
  const int jj = lane & 31;
  const bool act = jj < 10;
  const bool hi = lane >= 32;
  const int j = act ? jj : 9;
  const int o128w = hi ? 12 : 0, o64w = hi ? 10 : 8;  // 20-row offsets (WIDE)
  const int o128s = hi ? 8 : 0,  o64s = hi ? 6 : 4;   // 12-row offsets
  const int lB = lA + 1;
  f2 wiA[WIDE ? 5 : 3], whA[3], wiB[3], whB[3];
  if constexpr (WIDE) {
#pragma unroll
    for (int q = 0; q < 5; q++) {
      const int tb = hi ? (q < 4 ? 12 + 2 * q : 10) : 2 * q;
      wiA[q].x = p.wih[lA][j * 20 + tb];
      wiA[q].y = p.wih[lA][j * 20 + tb + 1];
    }
  } else {
#pragma unroll
    for (int q = 0; q < 3; q++) {
      const int tb = hi ? (q == 0 ? 8 : q == 1 ? 10 : 6) : 2 * q;
      wiA[q].x = tb     < 10 ? p.wih[lA][j * 10 + tb]     : 0.f;
      wiA[q].y = tb + 1 < 10 ? p.wih[lA][j * 10 + tb + 1] : 0.f;
    }
  }
#pragma unroll
  for (int q = 0; q < 3; q++) {
    const int tb = hi ? (q == 0 ? 8 : q == 1 ? 10 : 6) : 2 * q;
    whA[q].x = tb     < 10 ? p.whh[lA][j * 10 + tb]     : 0.f;
    whA[q].y = tb + 1 < 10 ? p.whh[lA][j * 10 + tb + 1] : 0.f;
    wiB[q].x = tb     < 10 ? p.wih[lB][j * 10 + tb]     : 0.f;
    wiB[q].y = tb + 1 < 10 ? p.wih[lB][j * 10 + tb + 1] : 0.f;
    whB[q].x = tb     < 10 ? p.whh[lB][j * 10 + tb]     : 0.f;
    whB[q].y = tb + 1 < 10 ? p.whh[lB][j * 10 + tb + 1] : 0.f;
  }
  const float bA = hi ? 0.f : (p.bih[lA][j] + p.bhh[lA][j]);
  const float bB = hi ? 0.f : (p.bih[lB][j] + p.bhh[lB][j]);

  const int rA = lA - 20;
  const float* yi0A = WIDE ? (y1f + 19 * Y1L + o128w) : (y2f + rin * Y2L + o128s);
  const float* yi0B = WIDE ? (y1f + 19 * Y1L + o64w)  : (y2f + rin * Y2L + o64s);
  const float* rArA = y2f + rA * Y2L + o128s;
  const float* rArB = y2f + rA * Y2L + o64s;
  float*       rAw  = y2f + rA * Y2L + j;
  const float* rBrA = y2f + (rA + 1) * Y2L + o128s;
  const float* rBrB = y2f + (rA + 1) * Y2L + o64s;
  float*       rBw  = y2f + (rA + 1) * Y2L + j;

  if constexpr (WIDE) {
    // zero ALL of y2 once (carry rows AND the [10],[11] pad slots read by hi
    // halves); consumers first read >= 12 barriers later, so this is race-free.
    for (int q = lane; q < 10 * Y2L; q += 64) y2f[q] = 0.f;
  }

  for (int s = 0; s < NSTEP2; s += 2) {
    if ((unsigned)(s - w) < (unsigned)NCH && act)
      s2pair_chunk<PH ? 1 : 0, WIDE>(yi0A, yi0B, rArA, rArB, rAw, rBrA, rBrB, rBw,
                                     wiA, whA, wiB, whB, bA, bB);
    __syncthreads();
    if ((unsigned)(s + 1 - w) < (unsigned)NCH && act)
      s2pair_chunk<PH ? 0 : 1, WIDE>(yi0A, yi0B, rArA, rArB, rAw, rBrA, rBrB, rBw,
                                     wiA, whA, wiB, whB, bA, bB);
    __syncthreads();
  }
}

// ================= kernel =================
// Layer -> wave map: w0: staging + proj + L30 + stores (skew 16).
// w1..w10: stack1 pairs (L0..L19). w11: L20,21 (rows 0,1, WIDE).
// w12: L22,23 (rows 2,3). w13: L24,25 (rows 4,5). w14: L26,27 (rows 6,7).
// w15: L28,29 (rows 8,9). Max serial chain per wave: 2 cells/timestep.
__global__ __launch_bounds__(1024, 1) void rnn_fused(P p) {
  __shared__ alignas(16) float xbuf[2 * CH * XROW];  // 4.3 KB staged x
  __shared__ alignas(16) float xw[2 * CH * 20];      // 1.3 KB projected input
  __shared__ alignas(16) float y1[20 * Y1L];         // 25.6 KB stack1 rings
  __shared__ alignas(16) float y2[10 * Y2L];         //  7.7 KB stack2 rings
  const int w = threadIdx.x >> 6, lane = threadIdx.x & 63, b = blockIdx.x;
  if (w == 0)       stage_proj(p, b, lane, xbuf, xw, y2 + 9 * Y2L);
  else if (w == 1)  pair_s1<true, true>(0, 1, p, lane, y1, xw);
  else if (w <= 10) {
    const int la = 2 * (w - 1);
    if (w & 1) pair_s1<true, false>(la, w, p, lane, y1, xw);
    else       pair_s1<false, false>(la, w, p, lane, y1, xw);
  }
  else if (w == 11) s2pair<true,  true >(20, 11, 0, p, lane, y1, y2);
  else if (w == 12) s2pair<false, false>(22, 12, 1, p, lane, y1, y2);
  else if (w == 13) s2pair<true,  false>(24, 13, 3, p, lane, y1, y2);
  else if (w == 14) s2pair<false, false>(26, 14, 5, p, lane, y1, y2);
  else              s2pair<true,  false>(28, 15, 7, p, lane, y1, y2);
}

extern "C" void kernel_launch(void* const* d_in, const int* in_sizes, int n_in,
                              void* d_out, int out_size, void* d_ws, size_t ws_size,
                              hipStream_t stream) {
  (void)in_sizes; (void)out_size; (void)d_ws; (void)ws_size;
  if (n_in < 21) return;
  P p{};
  p.x  = (const float*)d_in[0];
  p.w1 = (const float*)d_in[1];    // s1_wih0 (20x64)
  p.b1 = (const float*)d_in[3];    // s1_bih0
  p.wih[0] = nullptr;              p.whh[0] = (const float*)d_in[2];
  p.bih[0] = nullptr;              p.bhh[0] = (const float*)d_in[4];
  for (int l = 1; l < 20; l++) {
    p.wih[l] = (const float*)d_in[5] + (l - 1) * 400;
    p.whh[l] = (const float*)d_in[6] + (l - 1) * 400;
    p.bih[l] = (const float*)d_in[7] + (l - 1) * 20;
    p.bhh[l] = (const float*)d_in[8] + (l - 1) * 20;
  }
  p.wih[20] = (const float*)d_in[9];   p.whh[20] = (const float*)d_in[10];
  p.bih[20] = (const float*)d_in[11];  p.bhh[20] = (const float*)d_in[12];
  for (int l = 21; l < 30; l++) {
    p.wih[l] = (const float*)d_in[13] + (l - 21) * 100;
    p.whh[l] = (const float*)d_in[14] + (l - 21) * 100;
    p.bih[l] = (const float*)d_in[15] + (l - 21) * 10;
    p.bhh[l] = (const float*)d_in[16] + (l - 21) * 10;
  }
  p.wih[30] = (const float*)d_in[17];  p.whh[30] = (const float*)d_in[18];
  p.bih[30] = (const float*)d_in[19];  p.bhh[30] = (const float*)d_in[20];
  p.out = (float*)d_out;

  rnn_fused<<<B_, 1024, 0, stream>>>(p);
}

// Round 7
// 1607.457 us; speedup vs baseline: 3.4163x; 1.0241x over previous
//
#include <hip/hip_runtime.h>

#define DEVI __device__ __forceinline__
typedef float f2 __attribute__((ext_vector_type(2)));
typedef unsigned u32x2 __attribute__((ext_vector_type(2)));

// ---------------- problem constants ----------------
constexpr int T_ = 4096, B_ = 128;
constexpr int CH = 8, NCH = T_ / CH;   // 512 chunks of 8 timesteps
constexpr int NSTEP2 = 528;            // >= NCH + 16, even
constexpr int XROW = 68;               // x row padded 64->68 dwords

// One batch per workgroup. LDS strides in floats.
// y1/xw layer block: [2][CH][20] -> sl*CH*20 + tt*20 + j
// y2 layer block:    [2][CH][12] -> sl*CH*12 + tt*12 + j (slots 10,11 zero pads)
constexpr int Y1L = 2 * CH * 20;       // 320
constexpr int Y2L = 2 * CH * 12;       // 192

struct P {
  const float* x;
  const float* w1; const float* b1;    // wih0 (20x64), bih0 (20)
  const float* wih[31]; const float* whh[31];
  const float* bih[31]; const float* bhh[31];
  float* out;
};

DEVI float ftanh(float x) {
  float e = __builtin_amdgcn_exp2f(x * 2.8853900817779268f);
  return 1.0f - 2.0f * __builtin_amdgcn_rcpf(e + 1.0f);
}

DEVI f2 pfma(f2 a, f2 b, f2 c) { return __builtin_elementwise_fma(a, b, c); }

// uniform half-dot over 10 floats of a 20-row: 2 ds_read_b128 + 1 ds_read_b64.
// r128 = rowbase + (hi?12:0), r64 = rowbase + (hi?10:8); weights pre-reordered.
DEVI void acc20u(f2& a, const float* r128, const float* r64, const f2* w) {
  float4 v0 = ((const float4*)r128)[0];
  float4 v1 = ((const float4*)r128)[1];
  float2 v2 = *(const float2*)r64;
  union { float4 f; f2 h[2]; } u0, u1; u0.f = v0; u1.f = v1;
  f2 t; t.x = v2.x; t.y = v2.y;
  a = pfma(u0.h[0], w[0], a);
  a = pfma(u0.h[1], w[1], a);
  a = pfma(u1.h[0], w[2], a);
  a = pfma(u1.h[1], w[3], a);
  a = pfma(t, w[4], a);
}

// uniform half-dot over 6 slots of a 12-row: 1 b128 + 1 b64.
// r128 = rowbase + (hi?8:0), r64 = rowbase + (hi?6:4); weights pre-reordered.
DEVI void acc12u(f2& a, const float* r128, const float* r64, const f2* w) {
  float4 v0 = *(const float4*)r128;
  float2 v2 = *(const float2*)r64;
  union { float4 f; f2 h[2]; } u; u.f = v0;
  f2 t; t.x = v2.x; t.y = v2.y;
  a = pfma(u.h[0], w[0], a);
  a = pfma(u.h[1], w[1], a);
  a = pfma(t, w[2], a);
}

// full dot over 10 floats of a 12-padded row (off-chain, uniform): 2 b128 + 1 b64
DEVI float dot10(const float* r, const f2* w) {
  float4 v0 = ((const float4*)r)[0];
  float4 v1 = ((const float4*)r)[1];
  float2 v2 = *(const float2*)(r + 8);
  union { float4 f; f2 h[2]; } u0, u1; u0.f = v0; u1.f = v1;
  f2 a0{0.f, 0.f}, a1{0.f, 0.f};
  a0 = pfma(u0.h[0], w[0], a0);
  a1 = pfma(u0.h[1], w[1], a1);
  a0 = pfma(u1.h[0], w[2], a0);
  a1 = pfma(u1.h[1], w[3], a1);
  f2 t; t.x = v2.x; t.y = v2.y;
  a0 = pfma(t, w[4], a0);
  f2 s = a0 + a1;
  return s.x + s.y;
}

// combine the two lane-halves (lane j <-> lane j^32) via v_permlane32_swap_b32
// (VALU-class, off the LDS pipe). r.x + r.y == s[lane] + s[lane^32] in EVERY
// lane, so both halves get the full sum.
DEVI float redsum(f2 a) {
  const float s = a.x + a.y;
  u32x2 r = __builtin_amdgcn_permlane32_swap(__float_as_uint(s),
                                             __float_as_uint(s), false, false);
  return __uint_as_float(r.x) + __uint_as_float(r.y);
}

// ================= wave 0: x staging + input projection + L30 + stores ====
template <int SL>
DEVI void proj_chunk(const float* xbh, float* xww, const f2* wp, float bp,
                     bool hi) {
#pragma unroll
  for (int tt = 0; tt < CH; tt++) {
    const float* xr = xbh + SL * (CH * XROW) + tt * XROW;
    f2 a; a.x = bp; a.y = 0.f;
#pragma unroll
    for (int q = 0; q < 8; q++) {
      float4 v = ((const float4*)xr)[q];
      union { float4 f; f2 h[2]; } u; u.f = v;
      a = pfma(u.h[0], wp[2 * q], a);
      a = pfma(u.h[1], wp[2 * q + 1], a);
    }
    const float s = redsum(a);
    if (!hi) xww[SL * (CH * 20) + tt * 20] = s;
  }
}

// L30 (H=1): off-chain dot over L29's ring row + tiny scalar recurrence.
template <int SL>
DEVI void l30_chunk(const float* y29, const f2* wi30, float b30, float wh30,
                    float& h30, float*& optr, bool st) {
#pragma unroll
  for (int tt = 0; tt < CH; tt++) {
    const float d = dot10(y29 + SL * (CH * 12) + tt * 12, wi30);
    h30 = ftanh(fmaf(h30, wh30, d + b30));
    if (st) optr[tt * B_] = h30;
  }
  optr += CH * B_;
}

DEVI void stage_proj(const P& p, int b, int lane, float* xb, float* xwf,
                     const float* y29) {
  const int jj = lane & 31;
  const bool act = jj < 20;
  const bool hi = lane >= 32;
  const int j = act ? jj : 19;
  const int ko = hi ? 32 : 0;
  f2 wp[16];
#pragma unroll
  for (int k = 0; k < 16; k++) {
    wp[k].x = p.w1[j * 64 + ko + 2 * k]; wp[k].y = p.w1[j * 64 + ko + 2 * k + 1];
  }
  const float bp = hi ? 0.f : p.b1[j];
  float* xww = xwf + j;
  const float* xbh = xb + ko;

  // L30 state
  f2 wi30[5];
#pragma unroll
  for (int k = 0; k < 5; k++) {
    wi30[k].x = p.wih[30][2 * k];
    wi30[k].y = p.wih[30][2 * k + 1];
  }
  const float b30 = p.bih[30][0] + p.bhh[30][0];
  const float wh30 = p.whh[30][0];
  float h30 = 0.f;
  float* optr = p.out + b;
  const bool st = (lane == 0);

  // staging: 64 lanes x 2 float4 each covers CH*64 = 512 floats per chunk
  const int tq = lane >> 4, qq = lane & 15;
  const float* src[2]; int dst[2];
#pragma unroll
  for (int r = 0; r < 2; r++) {
    const int row = r * 4 + tq;          // 0..7
    src[r] = p.x + (size_t)row * (B_ * 64) + (size_t)b * 64 + qq * 4;
    dst[r] = row * XROW + qq * 4;
  }
  float4 pf[2];
#pragma unroll
  for (int r = 0; r < 2; r++) pf[r] = *(const float4*)src[r];
#pragma unroll
  for (int r = 0; r < 2; r++) *(float4*)(xb + dst[r]) = pf[r];
#pragma unroll
  for (int r = 0; r < 2; r++) src[r] += CH * B_ * 64;

  for (int s = 0; s < NSTEP2; s += 2) {
    {  // phase A: proj chunk c = s (slot 0), L30 chunk c = s-16 (slot 0)
      const int c = s;
      if (c < NCH) {
        const bool more = (c + 1 < NCH);
        float4 nx[2];
        if (more) {
#pragma unroll
          for (int r = 0; r < 2; r++) { nx[r] = *(const float4*)src[r]; src[r] += CH * B_ * 64; }
        }
        if (act) proj_chunk<0>(xbh, xww, wp, bp, hi);
        if (more) {
#pragma unroll
          for (int r = 0; r < 2; r++) *(float4*)(xb + CH * XROW + dst[r]) = nx[r];  // slot 1
        }
      }
      if ((unsigned)(s - 16) < (unsigned)NCH)
        l30_chunk<0>(y29, wi30, b30, wh30, h30, optr, st);
      __syncthreads();
    }
    {  // phase B: proj chunk c = s+1 (slot 1), L30 chunk c = s-15 (slot 1)
      const int c = s + 1;
      if (c < NCH) {
        const bool more = (c + 1 < NCH);
        float4 nx[2];
        if (more) {
#pragma unroll
          for (int r = 0; r < 2; r++) { nx[r] = *(const float4*)src[r]; src[r] += CH * B_ * 64; }
        }
        if (act) proj_chunk<1>(xbh, xww, wp, bp, hi);
        if (more) {
#pragma unroll
          for (int r = 0; r < 2; r++) *(float4*)(xb + dst[r]) = nx[r];  // slot 0
        }
      }
      if ((unsigned)(s + 1 - 16) < (unsigned)NCH)
        l30_chunk<1>(y29, wi30, b30, wh30, h30, optr, st);
      __syncthreads();
    }
  }
  if (st) p.out[T_ * B_ + b] = h30;  // hT
}

// ================= stack1 pair wave (2 layers, H=20) =================
// Software-pipelined: B(tt-1) is independent of A(tt); its issues fill A's
// LDS-read latency. Critical chain per phase = CH x A-cell only.
template <int SL, bool FIRST>
DEVI void pair_chunk(const float* yin, const float* yinB,
                     const float* yArA, const float* yArB, float* yAw,
                     const float* yBrA, const float* yBrB, float* yBw,
                     const f2* wiA, const f2* whA, const f2* wiB, const f2* whB,
                     float bA, float bB, bool hi) {
  constexpr int BASE = SL * (CH * 20);
  constexpr int PV0  = (1 - SL) * (CH * 20) + (CH - 1) * 20;
  {  // prologue: A(0)
    f2 a; a.x = bA; a.y = 0.f;
    if constexpr (FIRST) { const float pick = yin[BASE]; if (!hi) a.x += pick; }
    else acc20u(a, yin + BASE, yinB + BASE, wiA);
    acc20u(a, yArA + PV0, yArB + PV0, whA);
    yAw[BASE] = ftanh(redsum(a));
  }
#pragma unroll
  for (int tt = 1; tt < CH; tt++) {
    const int IN  = BASE + tt * 20;
    const int INp = IN - 20;
    const int PVB = (tt == 1) ? PV0 : (INp - 20);
    // B(tt-1): inputs all ready since last iteration
    f2 bb; bb.x = bB; bb.y = 0.f;
    acc20u(bb, yArA + INp, yArB + INp, wiB);
    acc20u(bb, yBrA + PVB, yBrB + PVB, whB);
    // A(tt): on-chain (reads A's row written last iteration)
    f2 a; a.x = bA; a.y = 0.f;
    if constexpr (FIRST) { const float pick = yin[IN]; if (!hi) a.x += pick; }
    else acc20u(a, yin + IN, yinB + IN, wiA);
    acc20u(a, yArA + INp, yArB + INp, whA);
    yBw[INp] = ftanh(redsum(bb));
    yAw[IN] = ftanh(redsum(a));
  }
  {  // epilogue: B(CH-1)
    const int IN = BASE + (CH - 1) * 20;
    f2 bb; bb.x = bB; bb.y = 0.f;
    acc20u(bb, yArA + IN, yArB + IN, wiB);
    acc20u(bb, yBrA + IN - 20, yBrB + IN - 20, whB);
    yBw[IN] = ftanh(redsum(bb));
  }
}

template <bool PH, bool FIRST>
DEVI void pair_s1(int la, int w, const P& p, int lane, float* y1f, float* xwf) {
  const int jj = lane & 31;
  const bool act = jj < 20;
  const bool hi = lane >= 32;
  const int j = act ? jj : 19;
  const int o128 = hi ? 12 : 0, o64 = hi ? 10 : 8;
  const int lb = la + 1;
  f2 whA[5], whB[5], wiB[5], wiA[FIRST ? 1 : 5];
#pragma unroll
  for (int q = 0; q < 5; q++) {
    const int tb = hi ? (q < 4 ? 12 + 2 * q : 10) : 2 * q;  // read-order term base
    whA[q].x = p.whh[la][j * 20 + tb]; whA[q].y = p.whh[la][j * 20 + tb + 1];
    whB[q].x = p.whh[lb][j * 20 + tb]; whB[q].y = p.whh[lb][j * 20 + tb + 1];
    wiB[q].x = p.wih[lb][j * 20 + tb]; wiB[q].y = p.wih[lb][j * 20 + tb + 1];
    if constexpr (!FIRST) {
      wiA[q].x = p.wih[la][j * 20 + tb]; wiA[q].y = p.wih[la][j * 20 + tb + 1];
    }
  }
  float bA = p.bhh[la][j];
  if constexpr (!FIRST) bA += p.bih[la][j];  // L0: bih folded into projection
  float bB = p.bih[lb][j] + p.bhh[lb][j];
  if (hi) { bA = 0.f; bB = 0.f; }

  const float* yin  = FIRST ? (xwf + j) : (y1f + (la - 1) * Y1L + o128);
  const float* yinB = FIRST ? nullptr   : (y1f + (la - 1) * Y1L + o64);
  const float* yArA = y1f + la * Y1L + o128;
  const float* yArB = y1f + la * Y1L + o64;
  float*       yAw  = y1f + la * Y1L + j;
  const float* yBrA = y1f + lb * Y1L + o128;
  const float* yBrB = y1f + lb * Y1L + o64;
  float*       yBw  = y1f + lb * Y1L + j;
  if (act) { yAw[(2 * CH - 1) * 20] = 0.f; yBw[(2 * CH - 1) * 20] = 0.f; }  // h(-1)=0

  for (int s = 0; s < NSTEP2; s += 2) {
    if ((unsigned)(s - w) < (unsigned)NCH && act)
      pair_chunk<PH ? 1 : 0, FIRST>(yin, yinB, yArA, yArB, yAw, yBrA, yBrB, yBw,
                                    wiA, whA, wiB, whB, bA, bB, hi);
    __syncthreads();
    if ((unsigned)(s + 1 - w) < (unsigned)NCH && act)
      pair_chunk<PH ? 0 : 1, FIRST>(yin, yinB, yArA, yArB, yAw, yBrA, yBrB, yBw,
                                    wiA, whA, wiB, whB, bA, bB, hi);
    __syncthreads();
  }
}

// ================= stack2 pair waves (2 layers, H=10) =================
// WIDE: first cell (L20) has a 20-wide input read from the stack-1 ring.
// Same software-pipelining as pair_chunk.
template <int SL, bool WIDE>
DEVI void s2pair_chunk(const float* yi0A, const float* yi0B,
                       const float* rArA, const float* rArB, float* rAw,
                       const float* rBrA, const float* rBrB, float* rBw,
                       const f2* wiA, const f2* whA, const f2* wiB, const f2* whB,
                       float bA, float bB) {
  constexpr int B1  = SL * (CH * 20);
  constexpr int B2  = SL * (CH * 12);
  constexpr int PV0 = (1 - SL) * (CH * 12) + (CH - 1) * 12;
  {  // prologue: A(0)
    f2 a; a.x = bA; a.y = 0.f;
    if constexpr (WIDE) acc20u(a, yi0A + B1, yi0B + B1, wiA);
    else                acc12u(a, yi0A + B2, yi0B + B2, wiA);
    acc12u(a, rArA + PV0, rArB + PV0, whA);
    rAw[B2] = ftanh(redsum(a));
  }
#pragma unroll
  for (int tt = 1; tt < CH; tt++) {
    const int IN2 = B2 + tt * 12;
    const int INp = IN2 - 12;
    const int PVB = (tt == 1) ? PV0 : (INp - 12);
    // B(tt-1)
    f2 bb; bb.x = bB; bb.y = 0.f;
    acc12u(bb, rArA + INp, rArB + INp, wiB);
    acc12u(bb, rBrA + PVB, rBrB + PVB, whB);
    // A(tt)
    f2 a; a.x = bA; a.y = 0.f;
    if constexpr (WIDE) { const int IN1 = B1 + tt * 20; acc20u(a, yi0A + IN1, yi0B + IN1, wiA); }
    else                acc12u(a, yi0A + IN2, yi0B + IN2, wiA);
    acc12u(a, rArA + INp, rArB + INp, whA);
    rBw[INp] = ftanh(redsum(bb));
    rAw[IN2] = ftanh(redsum(a));
  }
  {  // epilogue: B(CH-1)
    const int IN2 = B2 + (CH - 1) * 12;
    f2 bb; bb.x = bB; bb.y = 0.f;
    acc12u(bb, rArA + IN2, rArB + IN2, wiB);
    acc12u(bb, rBrA + IN2 - 12, rBrB + IN2 - 12, whB);
    rBw[IN2] = ftanh(redsum(bb));
  }
}

template <bool PH, bool WIDE>
DEVI void s2pair(int lA, int w, int rin, const P& p, int lane,
                 float* y1f, float* y2f) {
  const int jj = lane & 31;
  const bool act = jj < 10;
  const bool hi = lane >= 32;
  const int j = act ? jj : 9;
  const int o128w = hi ? 12 : 0, o64w = hi ? 10 : 8;  // 20-row offsets (WIDE)
  const int o128s = hi ? 8 : 0,  o64s = hi ? 6 : 4;   // 12-row offsets
  const int lB = lA + 1;
  f2 wiA[WIDE ? 5 : 3], whA[3], wiB[3], whB[3];
  if constexpr (WIDE) {
#pragma unroll
    for (int q = 0; q < 5; q++) {
      const int tb = hi ? (q < 4 ? 12 + 2 * q : 10) : 2 * q;
      wiA[q].x = p.wih[lA][j * 20 + tb];
      wiA[q].y = p.wih[lA][j * 20 + tb + 1];
    }
  } else {
#pragma unroll
    for (int q = 0; q < 3; q++) {
      const int tb = hi ? (q == 0 ? 8 : q == 1 ? 10 : 6) : 2 * q;
      wiA[q].x = tb     < 10 ? p.wih[lA][j * 10 + tb]     : 0.f;
      wiA[q].y = tb + 1 < 10 ? p.wih[lA][j * 10 + tb + 1] : 0.f;
    }
  }
#pragma unroll
  for (int q = 0; q < 3; q++) {
    const int tb = hi ? (q == 0 ? 8 : q == 1 ? 10 : 6) : 2 * q;
    whA[q].x = tb     < 10 ? p.whh[lA][j * 10 + tb]     : 0.f;
    whA[q].y = tb + 1 < 10 ? p.whh[lA][j * 10 + tb + 1] : 0.f;
    wiB[q].x = tb     < 10 ? p.wih[lB][j * 10 + tb]     : 0.f;
    wiB[q].y = tb + 1 < 10 ? p.wih[lB][j * 10 + tb + 1] : 0.f;
    whB[q].x = tb     < 10 ? p.whh[lB][j * 10 + tb]     : 0.f;
    whB[q].y = tb + 1 < 10 ? p.whh[lB][j * 10 + tb + 1] : 0.f;
  }
  const float bA = hi ? 0.f : (p.bih[lA][j] + p.bhh[lA][j]);
  const float bB = hi ? 0.f : (p.bih[lB][j] + p.bhh[lB][j]);

  const int rA = lA - 20;
  const float* yi0A = WIDE ? (y1f + 19 * Y1L + o128w) : (y2f + rin * Y2L + o128s);
  const float* yi0B = WIDE ? (y1f + 19 * Y1L + o64w)  : (y2f + rin * Y2L + o64s);
  const float* rArA = y2f + rA * Y2L + o128s;
  const float* rArB = y2f + rA * Y2L + o64s;
  float*       rAw  = y2f + rA * Y2L + j;
  const float* rBrA = y2f + (rA + 1) * Y2L + o128s;
  const float* rBrB = y2f + (rA + 1) * Y2L + o64s;
  float*       rBw  = y2f + (rA + 1) * Y2L + j;

  if constexpr (WIDE) {
    // zero ALL of y2 once (carry rows AND the [10],[11] pad slots read by hi
    // halves); consumers first read >= 12 barriers later, so this is race-free.
    for (int q = lane; q < 10 * Y2L; q += 64) y2f[q] = 0.f;
  }

  for (int s = 0; s < NSTEP2; s += 2) {
    if ((unsigned)(s - w) < (unsigned)NCH && act)
      s2pair_chunk<PH ? 1 : 0, WIDE>(yi0A, yi0B, rArA, rArB, rAw, rBrA, rBrB, rBw,
                                     wiA, whA, wiB, whB, bA, bB);
    __syncthreads();
    if ((unsigned)(s + 1 - w) < (unsigned)NCH && act)
      s2pair_chunk<PH ? 0 : 1, WIDE>(yi0A, yi0B, rArA, rArB, rAw, rBrA, rBrB, rBw,
                                     wiA, whA, wiB, whB, bA, bB);
    __syncthreads();
  }
}

// ================= kernel =================
// Layer -> wave map: w0: staging + proj + L30 + stores (skew 16).
// w1..w10: stack1 pairs (L0..L19). w11: L20,21 (rows 0,1, WIDE).
// w12: L22,23 (rows 2,3). w13: L24,25 (rows 4,5). w14: L26,27 (rows 6,7).
// w15: L28,29 (rows 8,9). Max serial chain per wave: 1 A-cell/timestep
// (B-cells software-pipelined one tt behind).
__global__ __launch_bounds__(1024, 1) void rnn_fused(P p) {
  __shared__ alignas(16) float xbuf[2 * CH * XROW];  // 4.3 KB staged x
  __shared__ alignas(16) float xw[2 * CH * 20];      // 1.3 KB projected input
  __shared__ alignas(16) float y1[20 * Y1L];         // 25.6 KB stack1 rings
  __shared__ alignas(16) float y2[10 * Y2L];         //  7.7 KB stack2 rings
  const int w = threadIdx.x >> 6, lane = threadIdx.x & 63, b = blockIdx.x;
  if (w == 0)       stage_proj(p, b, lane, xbuf, xw, y2 + 9 * Y2L);
  else if (w == 1)  pair_s1<true, true>(0, 1, p, lane, y1, xw);
  else if (w <= 10) {
    const int la = 2 * (w - 1);
    if (w & 1) pair_s1<true, false>(la, w, p, lane, y1, xw);
    else       pair_s1<false, false>(la, w, p, lane, y1, xw);
  }
  else if (w == 11) s2pair<true,  true >(20, 11, 0, p, lane, y1, y2);
  else if (w == 12) s2pair<false, false>(22, 12, 1, p, lane, y1, y2);
  else if (w == 13) s2pair<true,  false>(24, 13, 3, p, lane, y1, y2);
  else if (w == 14) s2pair<false, false>(26, 14, 5, p, lane, y1, y2);
  else              s2pair<true,  false>(28, 15, 7, p, lane, y1, y2);
}

extern "C" void kernel_launch(void* const* d_in, const int* in_sizes, int n_in,
                              void* d_out, int out_size, void* d_ws, size_t ws_size,
                              hipStream_t stream) {
  (void)in_sizes; (void)out_size; (void)d_ws; (void)ws_size;
  if (n_in < 21) return;
  P p{};
  p.x  = (const float*)d_in[0];
  p.w1 = (const float*)d_in[1];    // s1_wih0 (20x64)
  p.b1 = (const float*)d_in[3];    // s1_bih0
  p.wih[0] = nullptr;              p.whh[0] = (const float*)d_in[2];
  p.bih[0] = nullptr;              p.bhh[0] = (const float*)d_in[4];
  for (int l = 1; l < 20; l++) {
    p.wih[l] = (const float*)d_in[5] + (l - 1) * 400;
    p.whh[l] = (const float*)d_in[6] + (l - 1) * 400;
    p.bih[l] = (const float*)d_in[7] + (l - 1) * 20;
    p.bhh[l] = (const float*)d_in[8] + (l - 1) * 20;
  }
  p.wih[20] = (const float*)d_in[9];   p.whh[20] = (const float*)d_in[10];
  p.bih[20] = (const float*)d_in[11];  p.bhh[20] = (const float*)d_in[12];
  for (int l = 21; l < 30; l++) {
    p.wih[l] = (const float*)d_in[13] + (l - 21) * 100;
    p.whh[l] = (const float*)d_in[14] + (l - 21) * 100;
    p.bih[l] = (const float*)d_in[15] + (l - 21) * 10;
    p.bhh[l] = (const float*)d_in[16] + (l - 21) * 10;
  }
  p.wih[30] = (const float*)d_in[17];  p.whh[30] = (const float*)d_in[18];
  p.bih[30] = (const float*)d_in[19];  p.bhh[30] = (const float*)d_in[20];
  p.out = (float*)d_out;

  rnn_fused<<<B_, 1024, 0, stream>>>(p);
}